// Round 9
// baseline (300.760 us; speedup 1.0000x reference)
//
#include <hip/hip_runtime.h>

#define HPIX 256
#define WPIX 256
#define TSX 16
#define TSY 16
#define NTILE 256            // 16x16 tiles of 16x16 px
#define FCH 256
#define SEG_FLAT 16          // segments over all faces (fallback path)
#define NBUCK 4096           // minz counting-sort buckets over [1,2)
#define RSEG 8               // waves (bin segments) per quadrant block
#define BIGF 1000000000.0f
#define EPSF 1e-8f
#define MARGIN 0.125f
#define HP_SLOP 0.0625f      // >= 4x the FP eval error bound (~0.015 w-units)
#define EPSZ 1e-4f           // early-exit slack >> depth/minz FP error (~2e-6)
#define INIT_PACK 0xFFFFFFFFFFFFFFFFull

struct FaceRec {
  float x2, y2, a0, b0, a1, b1, inv, z0, z1, z2;
  float xmin, ymin, xmax, ymax;
};

// Compute the per-face record with EXACTLY the reference's op order (no FMA).
__device__ __forceinline__ FaceRec make_rec(const float* __restrict__ vb,
                                            const int* __restrict__ faces, int f) {
#pragma clang fp contract(off)
  FaceRec r;
  int i0 = faces[f * 3 + 0], i1 = faces[f * 3 + 1], i2 = faces[f * 3 + 2];
  float x0 = vb[i0 * 3 + 0], y0 = vb[i0 * 3 + 1], z0 = vb[i0 * 3 + 2];
  float x1 = vb[i1 * 3 + 0], y1 = vb[i1 * 3 + 1], z1 = vb[i1 * 3 + 2];
  float x2 = vb[i2 * 3 + 0], y2 = vb[i2 * 3 + 1], z2 = vb[i2 * 3 + 2];
  float px0 = x0 / z0, py0 = y0 / z0;
  float px1 = x1 / z1, py1 = y1 / z1;
  float px2 = x2 / z2, py2 = y2 / z2;
  float a0 = py1 - py2, b0 = px2 - px1;   // (y1-y2), (x2-x1)
  float a1 = py2 - py0, b1 = px0 - px2;   // (y2-y0), (x0-x2)
  float dy02 = py0 - py2;
  float denom = a0 * b1 + b0 * dy02;      // (y1-y2)*(x0-x2) + (x2-x1)*(y0-y2)
  bool nz = fabsf(denom) > EPSF;
  bool valid = nz && (z0 > 0.0f) && (z1 > 0.0f) && (z2 > 0.0f);
  r.x2 = px2; r.y2 = py2; r.a0 = a0; r.b0 = b0; r.a1 = a1; r.b1 = b1;
  r.inv = valid ? 1.0f / denom : 0.0f;
  r.z0 = z0; r.z1 = z1;
  r.z2 = valid ? z2 : -1.0f;              // invalid -> depth<0 -> fails depth>0
  if (valid) {
    r.xmin = fminf(px0, fminf(px1, px2)) - MARGIN;
    r.xmax = fmaxf(px0, fmaxf(px1, px2)) + MARGIN;
    r.ymin = fminf(py0, fminf(py1, py2)) - MARGIN;
    r.ymax = fmaxf(py0, fmaxf(py1, py2)) + MARGIN;
  } else {
    r.xmin = 2.0f * BIGF; r.xmax = -2.0f * BIGF;
    r.ymin = 2.0f * BIGF; r.ymax = -2.0f * BIGF;
  }
  return r;
}

// Same arithmetic as make_rec for the validity flag + minz (must match exactly).
__device__ __forceinline__ void classify(const float* __restrict__ vb,
                                         const int* __restrict__ faces, int f,
                                         bool& valid, float& minz) {
#pragma clang fp contract(off)
  int i0 = faces[f * 3 + 0], i1 = faces[f * 3 + 1], i2 = faces[f * 3 + 2];
  float x0 = vb[i0 * 3 + 0], y0 = vb[i0 * 3 + 1], z0 = vb[i0 * 3 + 2];
  float x1 = vb[i1 * 3 + 0], y1 = vb[i1 * 3 + 1], z1 = vb[i1 * 3 + 2];
  float x2 = vb[i2 * 3 + 0], y2 = vb[i2 * 3 + 1], z2 = vb[i2 * 3 + 2];
  float px0 = x0 / z0, py0 = y0 / z0;
  float px1 = x1 / z1, py1 = y1 / z1;
  float px2 = x2 / z2, py2 = y2 / z2;
  float a0 = py1 - py2, b0 = px2 - px1;
  float b1 = px0 - px2;
  float dy02 = py0 - py2;
  float denom = a0 * b1 + b0 * dy02;
  bool nz = fabsf(denom) > EPSF;
  valid = nz && (z0 > 0.0f) && (z1 > 0.0f) && (z2 > 0.0f);
  minz = fminf(z0, fminf(z1, z2));
}

// ---------- sorted path ----------
__global__ void key_hist_kernel(const float* __restrict__ verts,
                                const int* __restrict__ faces,
                                unsigned int* __restrict__ keys,
                                unsigned int* __restrict__ hist,
                                int V, int F, int NIMG) {
  int idx = blockIdx.x * blockDim.x + threadIdx.x;
  if (idx >= NIMG * F) return;
  int n = idx / F, f = idx - n * F;
  bool valid; float minz;
  classify(verts + (size_t)n * V * 3, faces, f, valid, minz);
  int b;
  if (!valid) b = NBUCK - 1;
  else {
    float t = (minz - 1.0f) * (float)NBUCK;
    b = (int)floorf(t);
    b = b < 0 ? 0 : (b > NBUCK - 1 ? NBUCK - 1 : b);
  }
  keys[idx] = (unsigned int)b;
  atomicAdd(&hist[n * NBUCK + b], 1u);
}

__global__ __launch_bounds__(1024) void scan_kernel(unsigned int* __restrict__ hist) {
  __shared__ unsigned int s[1024];
  unsigned int* h = hist + (size_t)blockIdx.x * NBUCK;
  int t = threadIdx.x;
  unsigned int v0 = h[4 * t], v1 = h[4 * t + 1], v2 = h[4 * t + 2], v3 = h[4 * t + 3];
  unsigned int sum = v0 + v1 + v2 + v3;
  s[t] = sum;
  __syncthreads();
  for (int off = 1; off < 1024; off <<= 1) {
    unsigned int x = (t >= off) ? s[t - off] : 0u;
    __syncthreads();
    s[t] += x;
    __syncthreads();
  }
  unsigned int excl = s[t] - sum;
  h[4 * t] = excl;
  h[4 * t + 1] = excl + v0;
  h[4 * t + 2] = excl + v0 + v1;
  h[4 * t + 3] = excl + v0 + v1 + v2;
}

// Scatter recs into minz-bucket-sorted order. o[2].z = key_lo (round-down
// bucket bound, <= true minz); o[2].w = original face id (bit transport).
__global__ void scatter_kernel(const float* __restrict__ verts,
                               const int* __restrict__ faces,
                               const unsigned int* __restrict__ keys,
                               unsigned int* __restrict__ hist,
                               float4* __restrict__ srecs,
                               int V, int F, int NIMG) {
  int idx = blockIdx.x * blockDim.x + threadIdx.x;
  if (idx >= NIMG * F) return;
  int n = idx / F, f = idx - n * F;
  const float* vb = verts + (size_t)n * V * 3;
  FaceRec r = make_rec(vb, faces, f);
  bool valid; float minz;
  classify(vb, faces, f, valid, minz);
  unsigned int b = keys[idx];
  // bucket 0 uses a sentinel so minz<1 robustness can't cause early-exit bugs
  float key_lo = (b == 0u) ? -3.0e38f
               : fminf(1.0f + (float)b * (1.0f / (float)NBUCK),
                       valid ? minz : 3.0e38f);
  unsigned int pos = atomicAdd(&hist[n * NBUCK + b], 1u);
  float4* o = srecs + ((size_t)n * F + pos) * 4;
  o[0] = make_float4(r.x2, r.y2, r.a0, r.b0);
  o[1] = make_float4(r.a1, r.b1, r.inv, r.z0);
  o[2] = make_float4(r.z1, r.z2, key_lo, __int_as_float(f));
  o[3] = make_float4(r.xmin, r.ymin, r.xmax, r.ymax);
}

// Order-preserving binning + per-tile pixel coverage mask. Bin ascending in
// sorted position (=> ascending key_lo). covmask[row] bit c = some kept
// face's padded bbox contains integer pixel (tile_x*16+c, tile_y*16+row).
__global__ __launch_bounds__(256) void bin_kernel(
    const float4* __restrict__ srecs, unsigned int* __restrict__ cursors,
    unsigned int* __restrict__ bins, unsigned int* __restrict__ covmask,
    int F) {
#pragma clang fp contract(off)
  const int t = blockIdx.x, n = blockIdx.y;
  const int tlx = t & 15, tly = t >> 4;
  const float X0 = (float)(tlx * TSX), X1 = X0 + (float)(TSX - 1);
  const float Y0 = (float)(tly * TSY), Y1 = Y0 + (float)(TSY - 1);
  __shared__ unsigned int s_cnt[4];
  __shared__ unsigned int s_cur;
  __shared__ unsigned int s_cov[16];
  const int tid = (int)threadIdx.x;
  const int lane = tid & 63, wid = tid >> 6;
  if (tid == 0) s_cur = 0u;
  if (tid < 16) s_cov[tid] = 0u;
  __syncthreads();
  const float4* rb = srecs + (size_t)n * F * 4;
  unsigned int* bin = bins + ((size_t)(n * NTILE + t)) * F;
  for (int base = 0; base < F; base += 256) {
    int j = base + tid;
    bool keep = false;
    if (j < F) {
      float4 D = rb[j * 4 + 3];
      keep = (D.x <= X1) && (D.z >= X0) && (D.y <= Y1) && (D.w >= Y0);
      if (keep) {
        float4 A = rb[j * 4 + 0];
        float4 B = rb[j * 4 + 1];
        float inv = B.z;
        if (fabsf(inv) <= 1.0f) {
          float m0 = -3.0e38f, m1 = -3.0e38f, m2 = -3.0e38f;
#pragma unroll
          for (int c = 0; c < 4; ++c) {
            float ccx = (c & 1) ? X1 : X0;
            float ccy = (c & 2) ? Y1 : Y0;
            float bx = ccx - A.x, by = ccy - A.y;
            float w0 = (A.z * bx + A.w * by) * inv;
            float w1 = (B.x * bx + B.y * by) * inv;
            float w2 = 1.0f - w0 - w1;
            m0 = fmaxf(m0, w0); m1 = fmaxf(m1, w1); m2 = fmaxf(m2, w2);
          }
          keep = (m0 >= -HP_SLOP) && (m1 >= -HP_SLOP) && (m2 >= -HP_SLOP);
        }
      }
      if (keep) {
        // integer pixels inside the padded bbox within this tile
        int cmin = (int)ceilf(D.x - X0);  cmin = cmin < 0 ? 0 : cmin;
        int cmax = (int)floorf(D.z - X0); cmax = cmax > 15 ? 15 : cmax;
        int rmin = (int)ceilf(D.y - Y0);  rmin = rmin < 0 ? 0 : rmin;
        int rmax = (int)floorf(D.w - Y0); rmax = rmax > 15 ? 15 : rmax;
        if (cmin <= cmax) {
          unsigned int colm = (0xFFFFu << cmin) & (0xFFFFu >> (15 - cmax));
          for (int r = rmin; r <= rmax; ++r) atomicOr(&s_cov[r], colm);
        }
      }
    }
    unsigned long long m = __ballot(keep);
    int cw = __popcll(m);
    if (lane == 0) s_cnt[wid] = (unsigned int)cw;
    __syncthreads();
    unsigned int woff = s_cur;
    for (int w = 0; w < wid; ++w) woff += s_cnt[w];
    unsigned int tot = s_cnt[0] + s_cnt[1] + s_cnt[2] + s_cnt[3];
    if (keep) {
      int off = __popcll(m & ((1ull << lane) - 1ull));
      bin[woff + (unsigned int)off] = (unsigned int)j;
    }
    __syncthreads();             // all reads of s_cur/s_cnt done
    if (tid == 0) s_cur += tot;
  }
  __syncthreads();
  if (tid == 0) cursors[n * NTILE + t] = s_cur;
  if (tid < 16) covmask[(size_t)(n * NTILE + t) * 16 + tid] = s_cov[tid];
}

// Epilogue: interpolate colors for the winning face, apply any-positive mask,
// write NCHW. Recomputes weights via make_rec -> bit-identical values.
__device__ __forceinline__ void emit_pixel(float* __restrict__ out,
    const float* __restrict__ vb, const float* __restrict__ colors,
    const int* __restrict__ faces, int n, int V, int C, int bestf,
    float cx, float cy, int row, int col) {
#pragma clang fp contract(off)
  float cv[8];
#pragma unroll
  for (int ch = 0; ch < 8; ++ch) cv[ch] = 0.0f;
  if (bestf >= 0) {
    int i0 = faces[bestf * 3 + 0], i1 = faces[bestf * 3 + 1], i2 = faces[bestf * 3 + 2];
    FaceRec r = make_rec(vb, faces, bestf);
    float bx = cx - r.x2, by = cy - r.y2;
    float w0 = (r.a0 * bx + r.b0 * by) * r.inv;
    float w1 = (r.a1 * bx + r.b1 * by) * r.inv;
    float w2 = 1.0f - w0 - w1;
    const float* c0 = colors + ((size_t)n * V + i0) * C;
    const float* c1 = colors + ((size_t)n * V + i1) * C;
    const float* c2 = colors + ((size_t)n * V + i2) * C;
    for (int ch = 0; ch < C && ch < 8; ++ch)
      cv[ch] = (w0 * c0[ch] + w1 * c1[ch]) + w2 * c2[ch];
  }
  bool anyp = false;
  for (int ch = 0; ch < C && ch < 8; ++ch) anyp = anyp || (cv[ch] > 0.0f);
  float m = anyp ? 1.0f : 0.0f;
  size_t base = (size_t)n * C * HPIX * WPIX + (size_t)row * WPIX + col;
  for (int ch = 0; ch < C && ch < 8; ++ch)
    out[base + (size_t)ch * HPIX * WPIX] = cv[ch] * m;
}

#define TESTF(Ak, Bk, Zk)                                                     \
  {                                                                           \
    float bx = cx - Ak.x, by = cy - Ak.y;                                     \
    float w0 = (Ak.z * bx + Ak.w * by) * Bk.z;                                \
    float w1 = (Bk.x * bx + Bk.y * by) * Bk.z;                                \
    float w2 = 1.0f - w0 - w1;                                                \
    float depth = (w0 * Bk.w + w1 * Zk.x) + w2 * Zk.y;                        \
    bool ok = (w0 >= 0.0f) && (w1 >= 0.0f) && (w2 >= 0.0f) && (depth > 0.0f); \
    if (ok) {                                                                 \
      unsigned int forig = (unsigned int)__float_as_int(Zk.w);                \
      unsigned long long p =                                                  \
          ((unsigned long long)__float_as_uint(depth) << 32) | forig;         \
      if (p < best) best = p;                                                 \
    }                                                                         \
  }

// 8 waves per 8x8 quadrant; wave w scans sorted subsequence {w, w+RSEG, ...}.
// Shared per-pixel depth cut in LDS (round 7). NEW: lanes whose pixel is
// outside EVERY kept face's padded bbox (coverage mask) skip the loop
// entirely -- provably bestf=-1 for them, and __all then runs over covered
// lanes only, so border waves exit at the covered convergence point instead
// of scanning the whole bin.
__global__ __launch_bounds__(512) void raster_sorted(
    const float4* __restrict__ srecs, const unsigned int* __restrict__ bins,
    const unsigned int* __restrict__ cursors,
    const unsigned int* __restrict__ covmask,
    const float* __restrict__ verts, const float* __restrict__ colors,
    const int* __restrict__ faces, float* __restrict__ out,
    int V, int F, int C) {
#pragma clang fp contract(off)
  __shared__ unsigned long long sdmin[64];
  const int bq = blockIdx.x;
  const int t = bq >> 2, quad = bq & 3;
  const int n = blockIdx.y;
  const int tlx = t & 15, tly = t >> 4;
  const int tid = (int)threadIdx.x;
  const int wave = tid >> 6, lane = tid & 63;
  const int tx = lane & 7, ty = lane >> 3;
  const int cloc = (quad & 1) * 8 + tx, rloc = (quad >> 1) * 8 + ty;
  const int col = tlx * TSX + cloc, row = tly * TSY + rloc;
  const float cx = (float)col, cy = (float)row;
  const float4* rb = srecs + (size_t)n * F * 4;
  const unsigned int* bin = bins + ((size_t)(n * NTILE + t)) * F;
  const int cnt = (int)cursors[n * NTILE + t];
  const bool covered =
      (covmask[(size_t)(n * NTILE + t) * 16 + rloc] >> cloc) & 1u;
  if (tid < 64) sdmin[tid] = INIT_PACK;
  __syncthreads();
  unsigned long long best = INIT_PACK;
  if (covered) {
    unsigned long long written = INIT_PACK;
    const int stride = 4 * RSEG;
    int i0 = wave;
    int j0 = 0, j1 = 0, j2 = 0, j3 = 0;
    if (i0 < cnt) {
      int c1i = i0 + RSEG     < cnt ? i0 + RSEG     : cnt - 1;
      int c2i = i0 + 2 * RSEG < cnt ? i0 + 2 * RSEG : cnt - 1;
      int c3i = i0 + 3 * RSEG < cnt ? i0 + 3 * RSEG : cnt - 1;
      j0 = (int)bin[i0]; j1 = (int)bin[c1i]; j2 = (int)bin[c2i]; j3 = (int)bin[c3i];
    }
    for (; i0 < cnt; i0 += stride) {
      // prefetch next batch's bin indices (removes one dependent round-trip)
      int ni = i0 + stride;
      int nj0 = 0, nj1 = 0, nj2 = 0, nj3 = 0;
      if (ni < cnt) {
        int d1 = ni + RSEG     < cnt ? ni + RSEG     : cnt - 1;
        int d2 = ni + 2 * RSEG < cnt ? ni + 2 * RSEG : cnt - 1;
        int d3 = ni + 3 * RSEG < cnt ? ni + 3 * RSEG : cnt - 1;
        nj0 = (int)bin[ni]; nj1 = (int)bin[d1]; nj2 = (int)bin[d2]; nj3 = (int)bin[d3];
      }
      float4 Z0 = rb[j0 * 4 + 2], Z1 = rb[j1 * 4 + 2];
      float4 Z2 = rb[j2 * 4 + 2], Z3 = rb[j3 * 4 + 2];
      float4 A0 = rb[j0 * 4 + 0], B0 = rb[j0 * 4 + 1];
      float4 A1 = rb[j1 * 4 + 0], B1 = rb[j1 * 4 + 1];
      float4 A2 = rb[j2 * 4 + 0], B2 = rb[j2 * 4 + 1];
      float4 A3 = rb[j3 * 4 + 0], B3 = rb[j3 * 4 + 1];
      // shared per-pixel depth cut (lags by at most one flush; only shrinks)
      unsigned long long sh = sdmin[lane];
      float dcut = __uint_as_float((unsigned int)(sh >> 32));  // NaN if INIT
      if (__all(Z0.z > dcut + EPSZ)) break;   // sorted: all later faces deeper
      TESTF(A0, B0, Z0);
      if (i0 + RSEG < cnt)     TESTF(A1, B1, Z1);
      if (i0 + 2 * RSEG < cnt) TESTF(A2, B2, Z2);
      if (i0 + 3 * RSEG < cnt) TESTF(A3, B3, Z3);
      if (best < written) { atomicMin(&sdmin[lane], best); written = best; }
      j0 = nj0; j1 = nj1; j2 = nj2; j3 = nj3;
    }
    if (best < written) atomicMin(&sdmin[lane], best);
  }
  __syncthreads();
  if (tid < 64) {
    unsigned long long b = sdmin[lane];
    int bestf = (b == INIT_PACK) ? -1 : (int)(unsigned int)(b & 0xFFFFFFFFull);
    emit_pixel(out, verts + (size_t)n * V * 3, colors, faces, n, V, C, bestf,
               cx, cy, row, col);
  }
}

// ---------- fallbacks (smaller ws) ----------
__global__ void prep_kernel(const float* __restrict__ verts,
                            const int* __restrict__ faces,
                            float4* __restrict__ recs, int V, int F, int NIMG) {
  int idx = blockIdx.x * blockDim.x + threadIdx.x;
  int total = NIMG * F;
  if (idx >= total) return;
  int n = idx / F, f = idx - n * F;
  FaceRec r = make_rec(verts + (size_t)n * V * 3, faces, f);
  float4* o = recs + (size_t)idx * 4;
  o[0] = make_float4(r.x2, r.y2, r.a0, r.b0);
  o[1] = make_float4(r.a1, r.b1, r.inv, r.z0);
  o[2] = make_float4(r.z1, r.z2, 0.0f, 0.0f);
  o[3] = make_float4(r.xmin, r.ymin, r.xmax, r.ymax);
}

__global__ void init_kernel(unsigned long long* __restrict__ packed, int npix) {
  int i = blockIdx.x * blockDim.x + threadIdx.x;
  if (i < npix) packed[i] = INIT_PACK;
}

__device__ __forceinline__ void test_face(float4 A, float4 B, float4 Z, int f,
                                          float cx, float cy,
                                          unsigned long long& best) {
#pragma clang fp contract(off)
  float bx = cx - A.x, by = cy - A.y;
  float w0 = (A.z * bx + A.w * by) * B.z;
  float w1 = (B.x * bx + B.y * by) * B.z;
  float w2 = 1.0f - w0 - w1;
  float depth = (w0 * B.w + w1 * Z.x) + w2 * Z.y;
  bool ok = (w0 >= 0.0f) && (w1 >= 0.0f) && (w2 >= 0.0f) && (depth > 0.0f);
  if (ok) {
    unsigned long long p =
        ((unsigned long long)__float_as_uint(depth) << 32) | (unsigned int)f;
    best = p < best ? p : best;
  }
}

__global__ __launch_bounds__(256) void raster_seg(
    const float4* __restrict__ recs, unsigned long long* __restrict__ packed,
    int F) {
  const int tx = threadIdx.x, ty = threadIdx.y;
  const int n = blockIdx.z / SEG_FLAT, s = blockIdx.z % SEG_FLAT;
  const int col = blockIdx.x * TSX + tx, row = blockIdx.y * TSY + ty;
  const float cx = (float)col, cy = (float)row;
  const float tX0 = (float)(blockIdx.x * TSX), tX1 = tX0 + (float)(TSX - 1);
  const float tY0 = (float)(blockIdx.y * TSY), tY1 = tY0 + (float)(TSY - 1);
  const float4* rb = recs + (size_t)n * F * 4;
  unsigned long long best = INIT_PACK;
  for (int f = s; f < F; f += SEG_FLAT) {
    float4 bb = rb[f * 4 + 3];
    if (bb.x > tX1 || bb.z < tX0 || bb.y > tY1 || bb.w < tY0) continue;
    float4 A = rb[f * 4 + 0];
    float4 B = rb[f * 4 + 1];
    float4 Z = rb[f * 4 + 2];
    test_face(A, B, Z, f, cx, cy, best);
  }
  if (best != INIT_PACK)
    atomicMin(&packed[(size_t)n * (HPIX * WPIX) + row * WPIX + col], best);
}

__global__ __launch_bounds__(256) void resolve_kernel(
    const unsigned long long* __restrict__ packed,
    const float* __restrict__ verts, const float* __restrict__ colors,
    const int* __restrict__ faces, float* __restrict__ out,
    int V, int F, int C, int NIMG) {
  int i = blockIdx.x * blockDim.x + threadIdx.x;
  int total = NIMG * HPIX * WPIX;
  if (i >= total) return;
  int n = i / (HPIX * WPIX);
  int pix = i - n * (HPIX * WPIX);
  int row = pix >> 8, col = pix & 255;
  unsigned long long p = packed[i];
  int bestf = (p == INIT_PACK) ? -1 : (int)(unsigned int)(p & 0xFFFFFFFFull);
  emit_pixel(out, verts + (size_t)n * V * 3, colors, faces, n, V, C, bestf,
             (float)col, (float)row, row, col);
}

__global__ __launch_bounds__(256) void raster_l(const float* __restrict__ verts,
    const float* __restrict__ colors, const int* __restrict__ faces,
    float* __restrict__ out, int V, int F, int C) {
#pragma clang fp contract(off)
  __shared__ float4 sA[FCH], sB[FCH], sZ[FCH], sD[FCH];
  const int n = blockIdx.z;
  const int tx = threadIdx.x, ty = threadIdx.y;
  const int tid = ty * TSX + tx;
  const int col = blockIdx.x * TSX + tx;
  const int row = blockIdx.y * TSY + ty;
  const float cx = (float)col, cy = (float)row;
  const float tX0 = (float)(blockIdx.x * TSX), tX1 = tX0 + (float)(TSX - 1);
  const float tY0 = (float)(blockIdx.y * TSY), tY1 = tY0 + (float)(TSY - 1);
  const float* vb = verts + (size_t)n * V * 3;
  float bestd = BIGF;
  int bestf = -1;
  for (int base = 0; base < F; base += FCH) {
    int cnt = min(FCH, F - base);
    if (tid < cnt) {
      FaceRec r = make_rec(vb, faces, base + tid);
      sA[tid] = make_float4(r.x2, r.y2, r.a0, r.b0);
      sB[tid] = make_float4(r.a1, r.b1, r.inv, r.z0);
      sZ[tid] = make_float4(r.z1, r.z2, 0.0f, 0.0f);
      sD[tid] = make_float4(r.xmin, r.ymin, r.xmax, r.ymax);
    }
    __syncthreads();
    for (int j = 0; j < cnt; ++j) {
      float4 bb = sD[j];
      if (bb.x > tX1 || bb.z < tX0 || bb.y > tY1 || bb.w < tY0) continue;
      float4 A = sA[j];
      float4 B = sB[j];
      float4 Z = sZ[j];
      float bx = cx - A.x, by = cy - A.y;
      float w0 = (A.z * bx + A.w * by) * B.z;
      float w1 = (B.x * bx + B.y * by) * B.z;
      float w2 = 1.0f - w0 - w1;
      float depth = (w0 * B.w + w1 * Z.x) + w2 * Z.y;
      bool ok = (w0 >= 0.0f) && (w1 >= 0.0f) && (w2 >= 0.0f) && (depth > 0.0f);
      float d = ok ? depth : BIGF;
      if (d < bestd) { bestd = d; bestf = base + j; }
    }
    __syncthreads();
  }
  emit_pixel(out, vb, colors, faces, n, V, C, bestf, cx, cy, row, col);
}

extern "C" void kernel_launch(void* const* d_in, const int* in_sizes, int n_in,
                              void* d_out, int out_size, void* d_ws, size_t ws_size,
                              hipStream_t stream) {
  const float* verts = (const float*)d_in[0];
  const float* colors = (const float*)d_in[1];
  const int* faces = (const int*)d_in[2];
  float* out = (float*)d_out;
  long long s0 = in_sizes[0], s1 = in_sizes[1], s2 = in_sizes[2];
  int C = (int)((3LL * s1) / s0);
  if (C < 1) C = 1;
  int NC = out_size / (HPIX * WPIX);
  int N = NC / C;
  if (N < 1) N = 1;
  int V = (int)(s0 / (3LL * N));
  int F = (int)(s2 / 3);

  // sorted-path ws layout: srecs | keys | hist | cursors | covmask | bins
  size_t offS = 0;
  size_t szS = (size_t)N * F * 4 * sizeof(float4);
  size_t offK = (offS + szS + 255) & ~(size_t)255;
  size_t szK = (size_t)N * F * sizeof(unsigned int);
  size_t offH = (offK + szK + 255) & ~(size_t)255;
  size_t szH = (size_t)N * NBUCK * sizeof(unsigned int);
  size_t offC2 = (offH + szH + 255) & ~(size_t)255;
  size_t szC2 = (size_t)N * NTILE * sizeof(unsigned int);
  size_t offCV = (offC2 + szC2 + 255) & ~(size_t)255;
  size_t szCV = (size_t)N * NTILE * 16 * sizeof(unsigned int);
  size_t offB2 = (offCV + szCV + 255) & ~(size_t)255;
  size_t szB2 = (size_t)N * NTILE * (size_t)F * sizeof(unsigned int);
  size_t need_sorted = offB2 + szB2;

  // fallback layout: recs | packed
  size_t szR = (size_t)N * F * 4 * sizeof(float4);
  size_t offP = (szR + 255) & ~(size_t)255;
  size_t szP = (size_t)N * HPIX * WPIX * sizeof(unsigned long long);

  dim3 block(TSX, TSY);
  char* ws = (char*)d_ws;
  int total = N * F;
  int npix = N * HPIX * WPIX;

  if (d_ws != nullptr && ws_size >= need_sorted) {
    float4* srecs = (float4*)(ws + offS);
    unsigned int* keys = (unsigned int*)(ws + offK);
    unsigned int* hist = (unsigned int*)(ws + offH);
    unsigned int* cursors = (unsigned int*)(ws + offC2);
    unsigned int* covmask = (unsigned int*)(ws + offCV);
    unsigned int* bins = (unsigned int*)(ws + offB2);
    hipMemsetAsync(hist, 0, szH, stream);
    key_hist_kernel<<<(total + 255) / 256, 256, 0, stream>>>(verts, faces, keys,
                                                             hist, V, F, N);
    scan_kernel<<<N, 1024, 0, stream>>>(hist);
    scatter_kernel<<<(total + 255) / 256, 256, 0, stream>>>(verts, faces, keys,
                                                            hist, srecs, V, F, N);
    bin_kernel<<<dim3(NTILE, N), 256, 0, stream>>>(srecs, cursors, bins,
                                                   covmask, F);
    raster_sorted<<<dim3(NTILE * 4, N), 512, 0, stream>>>(srecs, bins, cursors,
                                                          covmask, verts, colors,
                                                          faces, out, V, F, C);
  } else if (d_ws != nullptr && ws_size >= offP + szP) {
    float4* recs = (float4*)ws;
    unsigned long long* packed = (unsigned long long*)(ws + offP);
    init_kernel<<<(npix + 255) / 256, 256, 0, stream>>>(packed, npix);
    prep_kernel<<<(total + 255) / 256, 256, 0, stream>>>(verts, faces, recs, V, F, N);
    raster_seg<<<dim3(16, 16, N * SEG_FLAT), block, 0, stream>>>(recs, packed, F);
    resolve_kernel<<<(npix + 255) / 256, 256, 0, stream>>>(packed, verts, colors,
                                                           faces, out, V, F, C, N);
  } else {
    raster_l<<<dim3(16, 16, N), block, 0, stream>>>(verts, colors, faces, out,
                                                    V, F, C);
  }
}

// Round 10
// 194.181 us; speedup vs baseline: 1.5489x; 1.5489x over previous
//
#include <hip/hip_runtime.h>

#define HPIX 256
#define WPIX 256
#define TSX 16
#define TSY 16
#define NTILE 256            // 16x16 tiles of 16x16 px
#define FCH 256
#define SEG_FLAT 16          // segments over all faces (fallback path)
#define NBUCK 4096           // minz counting-sort buckets over [1,2)
#define RSEG 8               // waves (bin segments) per quadrant block
#define BIGF 1000000000.0f
#define EPSF 1e-8f
#define MARGIN 0.125f
#define HP_SLOP 0.0625f      // >= 4x the FP eval error bound (~0.015 w-units)
#define EPSZ 1e-4f           // early-exit slack >> depth/minz FP error (~2e-6)
#define INIT_PACK 0xFFFFFFFFFFFFFFFFull

struct FaceRec {
  float x2, y2, a0, b0, a1, b1, inv, z0, z1, z2;
  float xmin, ymin, xmax, ymax;
};

// Compute the per-face record with EXACTLY the reference's op order (no FMA).
__device__ __forceinline__ FaceRec make_rec(const float* __restrict__ vb,
                                            const int* __restrict__ faces, int f) {
#pragma clang fp contract(off)
  FaceRec r;
  int i0 = faces[f * 3 + 0], i1 = faces[f * 3 + 1], i2 = faces[f * 3 + 2];
  float x0 = vb[i0 * 3 + 0], y0 = vb[i0 * 3 + 1], z0 = vb[i0 * 3 + 2];
  float x1 = vb[i1 * 3 + 0], y1 = vb[i1 * 3 + 1], z1 = vb[i1 * 3 + 2];
  float x2 = vb[i2 * 3 + 0], y2 = vb[i2 * 3 + 1], z2 = vb[i2 * 3 + 2];
  float px0 = x0 / z0, py0 = y0 / z0;
  float px1 = x1 / z1, py1 = y1 / z1;
  float px2 = x2 / z2, py2 = y2 / z2;
  float a0 = py1 - py2, b0 = px2 - px1;   // (y1-y2), (x2-x1)
  float a1 = py2 - py0, b1 = px0 - px2;   // (y2-y0), (x0-x2)
  float dy02 = py0 - py2;
  float denom = a0 * b1 + b0 * dy02;      // (y1-y2)*(x0-x2) + (x2-x1)*(y0-y2)
  bool nz = fabsf(denom) > EPSF;
  bool valid = nz && (z0 > 0.0f) && (z1 > 0.0f) && (z2 > 0.0f);
  r.x2 = px2; r.y2 = py2; r.a0 = a0; r.b0 = b0; r.a1 = a1; r.b1 = b1;
  r.inv = valid ? 1.0f / denom : 0.0f;
  r.z0 = z0; r.z1 = z1;
  r.z2 = valid ? z2 : -1.0f;              // invalid -> depth<0 -> fails depth>0
  if (valid) {
    r.xmin = fminf(px0, fminf(px1, px2)) - MARGIN;
    r.xmax = fmaxf(px0, fmaxf(px1, px2)) + MARGIN;
    r.ymin = fminf(py0, fminf(py1, py2)) - MARGIN;
    r.ymax = fmaxf(py0, fmaxf(py1, py2)) + MARGIN;
  } else {
    r.xmin = 2.0f * BIGF; r.xmax = -2.0f * BIGF;
    r.ymin = 2.0f * BIGF; r.ymax = -2.0f * BIGF;
  }
  return r;
}

// Same arithmetic as make_rec for the validity flag + minz (must match exactly).
__device__ __forceinline__ void classify(const float* __restrict__ vb,
                                         const int* __restrict__ faces, int f,
                                         bool& valid, float& minz) {
#pragma clang fp contract(off)
  int i0 = faces[f * 3 + 0], i1 = faces[f * 3 + 1], i2 = faces[f * 3 + 2];
  float x0 = vb[i0 * 3 + 0], y0 = vb[i0 * 3 + 1], z0 = vb[i0 * 3 + 2];
  float x1 = vb[i1 * 3 + 0], y1 = vb[i1 * 3 + 1], z1 = vb[i1 * 3 + 2];
  float x2 = vb[i2 * 3 + 0], y2 = vb[i2 * 3 + 1], z2 = vb[i2 * 3 + 2];
  float px0 = x0 / z0, py0 = y0 / z0;
  float px1 = x1 / z1, py1 = y1 / z1;
  float px2 = x2 / z2, py2 = y2 / z2;
  float a0 = py1 - py2, b0 = px2 - px1;
  float b1 = px0 - px2;
  float dy02 = py0 - py2;
  float denom = a0 * b1 + b0 * dy02;
  bool nz = fabsf(denom) > EPSF;
  valid = nz && (z0 > 0.0f) && (z1 > 0.0f) && (z2 > 0.0f);
  minz = fminf(z0, fminf(z1, z2));
}

// ---------- sorted path ----------
__global__ void key_hist_kernel(const float* __restrict__ verts,
                                const int* __restrict__ faces,
                                unsigned int* __restrict__ keys,
                                unsigned int* __restrict__ hist,
                                int V, int F, int NIMG) {
  int idx = blockIdx.x * blockDim.x + threadIdx.x;
  if (idx >= NIMG * F) return;
  int n = idx / F, f = idx - n * F;
  bool valid; float minz;
  classify(verts + (size_t)n * V * 3, faces, f, valid, minz);
  int b;
  if (!valid) b = NBUCK - 1;
  else {
    float t = (minz - 1.0f) * (float)NBUCK;
    b = (int)floorf(t);
    b = b < 0 ? 0 : (b > NBUCK - 1 ? NBUCK - 1 : b);
  }
  keys[idx] = (unsigned int)b;
  atomicAdd(&hist[n * NBUCK + b], 1u);
}

__global__ __launch_bounds__(1024) void scan_kernel(unsigned int* __restrict__ hist) {
  __shared__ unsigned int s[1024];
  unsigned int* h = hist + (size_t)blockIdx.x * NBUCK;
  int t = threadIdx.x;
  unsigned int v0 = h[4 * t], v1 = h[4 * t + 1], v2 = h[4 * t + 2], v3 = h[4 * t + 3];
  unsigned int sum = v0 + v1 + v2 + v3;
  s[t] = sum;
  __syncthreads();
  for (int off = 1; off < 1024; off <<= 1) {
    unsigned int x = (t >= off) ? s[t - off] : 0u;
    __syncthreads();
    s[t] += x;
    __syncthreads();
  }
  unsigned int excl = s[t] - sum;
  h[4 * t] = excl;
  h[4 * t + 1] = excl + v0;
  h[4 * t + 2] = excl + v0 + v1;
  h[4 * t + 3] = excl + v0 + v1 + v2;
}

// Scatter recs into minz-bucket-sorted order. o[2].z = key_lo (round-down
// bucket bound, <= true minz); o[2].w = original face id (bit transport).
__global__ void scatter_kernel(const float* __restrict__ verts,
                               const int* __restrict__ faces,
                               const unsigned int* __restrict__ keys,
                               unsigned int* __restrict__ hist,
                               float4* __restrict__ srecs,
                               int V, int F, int NIMG) {
  int idx = blockIdx.x * blockDim.x + threadIdx.x;
  if (idx >= NIMG * F) return;
  int n = idx / F, f = idx - n * F;
  const float* vb = verts + (size_t)n * V * 3;
  FaceRec r = make_rec(vb, faces, f);
  bool valid; float minz;
  classify(vb, faces, f, valid, minz);
  unsigned int b = keys[idx];
  // bucket 0 uses a sentinel so minz<1 robustness can't cause early-exit bugs
  float key_lo = (b == 0u) ? -3.0e38f
               : fminf(1.0f + (float)b * (1.0f / (float)NBUCK),
                       valid ? minz : 3.0e38f);
  unsigned int pos = atomicAdd(&hist[n * NBUCK + b], 1u);
  float4* o = srecs + ((size_t)n * F + pos) * 4;
  o[0] = make_float4(r.x2, r.y2, r.a0, r.b0);
  o[1] = make_float4(r.a1, r.b1, r.inv, r.z0);
  o[2] = make_float4(r.z1, r.z2, key_lo, __int_as_float(f));
  o[3] = make_float4(r.xmin, r.ymin, r.xmax, r.ymax);
}

// Order-preserving binning + per-tile pixel coverage mask. Coverage is
// accumulated per-lane in REGISTERS (4 x u64 = 16 rows x 16 cols), reduced
// once at the end via shfl-xor butterfly -- no LDS atomics (round-9 lesson:
// same-address LDS atomicOr serialized ~4000 deep, 7x kernel slowdown).
__global__ __launch_bounds__(256) void bin_kernel(
    const float4* __restrict__ srecs, unsigned int* __restrict__ cursors,
    unsigned int* __restrict__ bins, unsigned int* __restrict__ covmask,
    int F) {
#pragma clang fp contract(off)
  const int t = blockIdx.x, n = blockIdx.y;
  const int tlx = t & 15, tly = t >> 4;
  const float X0 = (float)(tlx * TSX), X1 = X0 + (float)(TSX - 1);
  const float Y0 = (float)(tly * TSY), Y1 = Y0 + (float)(TSY - 1);
  __shared__ unsigned int s_cnt[4];
  __shared__ unsigned int s_cur;
  __shared__ unsigned long long s_wcov[4][4];
  const int tid = (int)threadIdx.x;
  const int lane = tid & 63, wid = tid >> 6;
  if (tid == 0) s_cur = 0u;
  __syncthreads();
  const float4* rb = srecs + (size_t)n * F * 4;
  unsigned int* bin = bins + ((size_t)(n * NTILE + t)) * F;
  unsigned long long cov[4] = {0ull, 0ull, 0ull, 0ull};  // rows 0-3,4-7,8-11,12-15
  for (int base = 0; base < F; base += 256) {
    int j = base + tid;
    bool keep = false;
    if (j < F) {
      float4 D = rb[j * 4 + 3];
      keep = (D.x <= X1) && (D.z >= X0) && (D.y <= Y1) && (D.w >= Y0);
      if (keep) {
        float4 A = rb[j * 4 + 0];
        float4 B = rb[j * 4 + 1];
        float inv = B.z;
        if (fabsf(inv) <= 1.0f) {
          float m0 = -3.0e38f, m1 = -3.0e38f, m2 = -3.0e38f;
#pragma unroll
          for (int c = 0; c < 4; ++c) {
            float ccx = (c & 1) ? X1 : X0;
            float ccy = (c & 2) ? Y1 : Y0;
            float bx = ccx - A.x, by = ccy - A.y;
            float w0 = (A.z * bx + A.w * by) * inv;
            float w1 = (B.x * bx + B.y * by) * inv;
            float w2 = 1.0f - w0 - w1;
            m0 = fmaxf(m0, w0); m1 = fmaxf(m1, w1); m2 = fmaxf(m2, w2);
          }
          keep = (m0 >= -HP_SLOP) && (m1 >= -HP_SLOP) && (m2 >= -HP_SLOP);
        }
      }
      if (keep) {
        // integer pixels inside the padded bbox within this tile
        int cmin = (int)ceilf(D.x - X0);  cmin = cmin < 0 ? 0 : cmin;
        int cmax = (int)floorf(D.z - X0); cmax = cmax > 15 ? 15 : cmax;
        int rmin = (int)ceilf(D.y - Y0);  rmin = rmin < 0 ? 0 : rmin;
        int rmax = (int)floorf(D.w - Y0); rmax = rmax > 15 ? 15 : rmax;
        if (cmin <= cmax && rmin <= rmax) {
          unsigned int colm = (0xFFFFu << cmin) & (0xFFFFu >> (15 - cmax));
          unsigned int rowm = (0xFFFFu << rmin) & (0xFFFFu >> (15 - rmax));
          unsigned long long rep =
              (unsigned long long)colm * 0x0001000100010001ull;
#pragma unroll
          for (int k = 0; k < 4; ++k) {
            unsigned int rm4 = (rowm >> (4 * k)) & 0xFu;
            unsigned long long mk =
                ((rm4 & 1u) ? 0x000000000000FFFFull : 0ull) |
                ((rm4 & 2u) ? 0x00000000FFFF0000ull : 0ull) |
                ((rm4 & 4u) ? 0x0000FFFF00000000ull : 0ull) |
                ((rm4 & 8u) ? 0xFFFF000000000000ull : 0ull);
            cov[k] |= rep & mk;
          }
        }
      }
    }
    unsigned long long m = __ballot(keep);
    int cw = __popcll(m);
    if (lane == 0) s_cnt[wid] = (unsigned int)cw;
    __syncthreads();
    unsigned int woff = s_cur;
    for (int w = 0; w < wid; ++w) woff += s_cnt[w];
    unsigned int tot = s_cnt[0] + s_cnt[1] + s_cnt[2] + s_cnt[3];
    if (keep) {
      int off = __popcll(m & ((1ull << lane) - 1ull));
      bin[woff + (unsigned int)off] = (unsigned int)j;
    }
    __syncthreads();             // all reads of s_cur/s_cnt done
    if (tid == 0) s_cur += tot;
  }
  // one butterfly OR-reduce per wave (once per kernel, not per chunk)
#pragma unroll
  for (int off = 1; off < 64; off <<= 1) {
#pragma unroll
    for (int k = 0; k < 4; ++k)
      cov[k] |= __shfl_xor(cov[k], off);
  }
  if (lane == 0) {
#pragma unroll
    for (int k = 0; k < 4; ++k) s_wcov[wid][k] = cov[k];
  }
  __syncthreads();
  if (tid == 0) cursors[n * NTILE + t] = s_cur;
  if (tid < 16) {
    int r = tid, k = r >> 2, sh = (r & 3) * 16;
    unsigned int v = 0u;
#pragma unroll
    for (int w = 0; w < 4; ++w)
      v |= (unsigned int)((s_wcov[w][k] >> sh) & 0xFFFFull);
    covmask[(size_t)(n * NTILE + t) * 16 + r] = v;
  }
}

// Epilogue: interpolate colors for the winning face, apply any-positive mask,
// write NCHW. Recomputes weights via make_rec -> bit-identical values.
__device__ __forceinline__ void emit_pixel(float* __restrict__ out,
    const float* __restrict__ vb, const float* __restrict__ colors,
    const int* __restrict__ faces, int n, int V, int C, int bestf,
    float cx, float cy, int row, int col) {
#pragma clang fp contract(off)
  float cv[8];
#pragma unroll
  for (int ch = 0; ch < 8; ++ch) cv[ch] = 0.0f;
  if (bestf >= 0) {
    int i0 = faces[bestf * 3 + 0], i1 = faces[bestf * 3 + 1], i2 = faces[bestf * 3 + 2];
    FaceRec r = make_rec(vb, faces, bestf);
    float bx = cx - r.x2, by = cy - r.y2;
    float w0 = (r.a0 * bx + r.b0 * by) * r.inv;
    float w1 = (r.a1 * bx + r.b1 * by) * r.inv;
    float w2 = 1.0f - w0 - w1;
    const float* c0 = colors + ((size_t)n * V + i0) * C;
    const float* c1 = colors + ((size_t)n * V + i1) * C;
    const float* c2 = colors + ((size_t)n * V + i2) * C;
    for (int ch = 0; ch < C && ch < 8; ++ch)
      cv[ch] = (w0 * c0[ch] + w1 * c1[ch]) + w2 * c2[ch];
  }
  bool anyp = false;
  for (int ch = 0; ch < C && ch < 8; ++ch) anyp = anyp || (cv[ch] > 0.0f);
  float m = anyp ? 1.0f : 0.0f;
  size_t base = (size_t)n * C * HPIX * WPIX + (size_t)row * WPIX + col;
  for (int ch = 0; ch < C && ch < 8; ++ch)
    out[base + (size_t)ch * HPIX * WPIX] = cv[ch] * m;
}

#define TESTF(Ak, Bk, Zk)                                                     \
  {                                                                           \
    float bx = cx - Ak.x, by = cy - Ak.y;                                     \
    float w0 = (Ak.z * bx + Ak.w * by) * Bk.z;                                \
    float w1 = (Bk.x * bx + Bk.y * by) * Bk.z;                                \
    float w2 = 1.0f - w0 - w1;                                                \
    float depth = (w0 * Bk.w + w1 * Zk.x) + w2 * Zk.y;                        \
    bool ok = (w0 >= 0.0f) && (w1 >= 0.0f) && (w2 >= 0.0f) && (depth > 0.0f); \
    if (ok) {                                                                 \
      unsigned int forig = (unsigned int)__float_as_int(Zk.w);                \
      unsigned long long p =                                                  \
          ((unsigned long long)__float_as_uint(depth) << 32) | forig;         \
      if (p < best) best = p;                                                 \
    }                                                                         \
  }

// 8 waves per 8x8 quadrant; wave w scans sorted subsequence {w, w+RSEG, ...}.
// Shared per-pixel depth cut in LDS. Lanes whose pixel is outside EVERY kept
// face's padded bbox (coverage mask) skip the loop entirely -- provably
// bestf=-1 for them, and __all then runs over covered lanes only, so border
// waves exit at the covered convergence point instead of scanning the bin.
__global__ __launch_bounds__(512) void raster_sorted(
    const float4* __restrict__ srecs, const unsigned int* __restrict__ bins,
    const unsigned int* __restrict__ cursors,
    const unsigned int* __restrict__ covmask,
    const float* __restrict__ verts, const float* __restrict__ colors,
    const int* __restrict__ faces, float* __restrict__ out,
    int V, int F, int C) {
#pragma clang fp contract(off)
  __shared__ unsigned long long sdmin[64];
  const int bq = blockIdx.x;
  const int t = bq >> 2, quad = bq & 3;
  const int n = blockIdx.y;
  const int tlx = t & 15, tly = t >> 4;
  const int tid = (int)threadIdx.x;
  const int wave = tid >> 6, lane = tid & 63;
  const int tx = lane & 7, ty = lane >> 3;
  const int cloc = (quad & 1) * 8 + tx, rloc = (quad >> 1) * 8 + ty;
  const int col = tlx * TSX + cloc, row = tly * TSY + rloc;
  const float cx = (float)col, cy = (float)row;
  const float4* rb = srecs + (size_t)n * F * 4;
  const unsigned int* bin = bins + ((size_t)(n * NTILE + t)) * F;
  const int cnt = (int)cursors[n * NTILE + t];
  const bool covered =
      (covmask[(size_t)(n * NTILE + t) * 16 + rloc] >> cloc) & 1u;
  if (tid < 64) sdmin[tid] = INIT_PACK;
  __syncthreads();
  unsigned long long best = INIT_PACK;
  if (covered) {
    unsigned long long written = INIT_PACK;
    const int stride = 4 * RSEG;
    int i0 = wave;
    int j0 = 0, j1 = 0, j2 = 0, j3 = 0;
    if (i0 < cnt) {
      int c1i = i0 + RSEG     < cnt ? i0 + RSEG     : cnt - 1;
      int c2i = i0 + 2 * RSEG < cnt ? i0 + 2 * RSEG : cnt - 1;
      int c3i = i0 + 3 * RSEG < cnt ? i0 + 3 * RSEG : cnt - 1;
      j0 = (int)bin[i0]; j1 = (int)bin[c1i]; j2 = (int)bin[c2i]; j3 = (int)bin[c3i];
    }
    for (; i0 < cnt; i0 += stride) {
      // prefetch next batch's bin indices (removes one dependent round-trip)
      int ni = i0 + stride;
      int nj0 = 0, nj1 = 0, nj2 = 0, nj3 = 0;
      if (ni < cnt) {
        int d1 = ni + RSEG     < cnt ? ni + RSEG     : cnt - 1;
        int d2 = ni + 2 * RSEG < cnt ? ni + 2 * RSEG : cnt - 1;
        int d3 = ni + 3 * RSEG < cnt ? ni + 3 * RSEG : cnt - 1;
        nj0 = (int)bin[ni]; nj1 = (int)bin[d1]; nj2 = (int)bin[d2]; nj3 = (int)bin[d3];
      }
      float4 Z0 = rb[j0 * 4 + 2], Z1 = rb[j1 * 4 + 2];
      float4 Z2 = rb[j2 * 4 + 2], Z3 = rb[j3 * 4 + 2];
      float4 A0 = rb[j0 * 4 + 0], B0 = rb[j0 * 4 + 1];
      float4 A1 = rb[j1 * 4 + 0], B1 = rb[j1 * 4 + 1];
      float4 A2 = rb[j2 * 4 + 0], B2 = rb[j2 * 4 + 1];
      float4 A3 = rb[j3 * 4 + 0], B3 = rb[j3 * 4 + 1];
      // shared per-pixel depth cut (lags by at most one flush; only shrinks)
      unsigned long long sh = sdmin[lane];
      float dcut = __uint_as_float((unsigned int)(sh >> 32));  // NaN if INIT
      if (__all(Z0.z > dcut + EPSZ)) break;   // sorted: all later faces deeper
      TESTF(A0, B0, Z0);
      if (i0 + RSEG < cnt)     TESTF(A1, B1, Z1);
      if (i0 + 2 * RSEG < cnt) TESTF(A2, B2, Z2);
      if (i0 + 3 * RSEG < cnt) TESTF(A3, B3, Z3);
      if (best < written) { atomicMin(&sdmin[lane], best); written = best; }
      j0 = nj0; j1 = nj1; j2 = nj2; j3 = nj3;
    }
    if (best < written) atomicMin(&sdmin[lane], best);
  }
  __syncthreads();
  if (tid < 64) {
    unsigned long long b = sdmin[lane];
    int bestf = (b == INIT_PACK) ? -1 : (int)(unsigned int)(b & 0xFFFFFFFFull);
    emit_pixel(out, verts + (size_t)n * V * 3, colors, faces, n, V, C, bestf,
               cx, cy, row, col);
  }
}

// ---------- fallbacks (smaller ws) ----------
__global__ void prep_kernel(const float* __restrict__ verts,
                            const int* __restrict__ faces,
                            float4* __restrict__ recs, int V, int F, int NIMG) {
  int idx = blockIdx.x * blockDim.x + threadIdx.x;
  int total = NIMG * F;
  if (idx >= total) return;
  int n = idx / F, f = idx - n * F;
  FaceRec r = make_rec(verts + (size_t)n * V * 3, faces, f);
  float4* o = recs + (size_t)idx * 4;
  o[0] = make_float4(r.x2, r.y2, r.a0, r.b0);
  o[1] = make_float4(r.a1, r.b1, r.inv, r.z0);
  o[2] = make_float4(r.z1, r.z2, 0.0f, 0.0f);
  o[3] = make_float4(r.xmin, r.ymin, r.xmax, r.ymax);
}

__global__ void init_kernel(unsigned long long* __restrict__ packed, int npix) {
  int i = blockIdx.x * blockDim.x + threadIdx.x;
  if (i < npix) packed[i] = INIT_PACK;
}

__device__ __forceinline__ void test_face(float4 A, float4 B, float4 Z, int f,
                                          float cx, float cy,
                                          unsigned long long& best) {
#pragma clang fp contract(off)
  float bx = cx - A.x, by = cy - A.y;
  float w0 = (A.z * bx + A.w * by) * B.z;
  float w1 = (B.x * bx + B.y * by) * B.z;
  float w2 = 1.0f - w0 - w1;
  float depth = (w0 * B.w + w1 * Z.x) + w2 * Z.y;
  bool ok = (w0 >= 0.0f) && (w1 >= 0.0f) && (w2 >= 0.0f) && (depth > 0.0f);
  if (ok) {
    unsigned long long p =
        ((unsigned long long)__float_as_uint(depth) << 32) | (unsigned int)f;
    best = p < best ? p : best;
  }
}

__global__ __launch_bounds__(256) void raster_seg(
    const float4* __restrict__ recs, unsigned long long* __restrict__ packed,
    int F) {
  const int tx = threadIdx.x, ty = threadIdx.y;
  const int n = blockIdx.z / SEG_FLAT, s = blockIdx.z % SEG_FLAT;
  const int col = blockIdx.x * TSX + tx, row = blockIdx.y * TSY + ty;
  const float cx = (float)col, cy = (float)row;
  const float tX0 = (float)(blockIdx.x * TSX), tX1 = tX0 + (float)(TSX - 1);
  const float tY0 = (float)(blockIdx.y * TSY), tY1 = tY0 + (float)(TSY - 1);
  const float4* rb = recs + (size_t)n * F * 4;
  unsigned long long best = INIT_PACK;
  for (int f = s; f < F; f += SEG_FLAT) {
    float4 bb = rb[f * 4 + 3];
    if (bb.x > tX1 || bb.z < tX0 || bb.y > tY1 || bb.w < tY0) continue;
    float4 A = rb[f * 4 + 0];
    float4 B = rb[f * 4 + 1];
    float4 Z = rb[f * 4 + 2];
    test_face(A, B, Z, f, cx, cy, best);
  }
  if (best != INIT_PACK)
    atomicMin(&packed[(size_t)n * (HPIX * WPIX) + row * WPIX + col], best);
}

__global__ __launch_bounds__(256) void resolve_kernel(
    const unsigned long long* __restrict__ packed,
    const float* __restrict__ verts, const float* __restrict__ colors,
    const int* __restrict__ faces, float* __restrict__ out,
    int V, int F, int C, int NIMG) {
  int i = blockIdx.x * blockDim.x + threadIdx.x;
  int total = NIMG * HPIX * WPIX;
  if (i >= total) return;
  int n = i / (HPIX * WPIX);
  int pix = i - n * (HPIX * WPIX);
  int row = pix >> 8, col = pix & 255;
  unsigned long long p = packed[i];
  int bestf = (p == INIT_PACK) ? -1 : (int)(unsigned int)(p & 0xFFFFFFFFull);
  emit_pixel(out, verts + (size_t)n * V * 3, colors, faces, n, V, C, bestf,
             (float)col, (float)row, row, col);
}

__global__ __launch_bounds__(256) void raster_l(const float* __restrict__ verts,
    const float* __restrict__ colors, const int* __restrict__ faces,
    float* __restrict__ out, int V, int F, int C) {
#pragma clang fp contract(off)
  __shared__ float4 sA[FCH], sB[FCH], sZ[FCH], sD[FCH];
  const int n = blockIdx.z;
  const int tx = threadIdx.x, ty = threadIdx.y;
  const int tid = ty * TSX + tx;
  const int col = blockIdx.x * TSX + tx;
  const int row = blockIdx.y * TSY + ty;
  const float cx = (float)col, cy = (float)row;
  const float tX0 = (float)(blockIdx.x * TSX), tX1 = tX0 + (float)(TSX - 1);
  const float tY0 = (float)(blockIdx.y * TSY), tY1 = tY0 + (float)(TSY - 1);
  const float* vb = verts + (size_t)n * V * 3;
  float bestd = BIGF;
  int bestf = -1;
  for (int base = 0; base < F; base += FCH) {
    int cnt = min(FCH, F - base);
    if (tid < cnt) {
      FaceRec r = make_rec(vb, faces, base + tid);
      sA[tid] = make_float4(r.x2, r.y2, r.a0, r.b0);
      sB[tid] = make_float4(r.a1, r.b1, r.inv, r.z0);
      sZ[tid] = make_float4(r.z1, r.z2, 0.0f, 0.0f);
      sD[tid] = make_float4(r.xmin, r.ymin, r.xmax, r.ymax);
    }
    __syncthreads();
    for (int j = 0; j < cnt; ++j) {
      float4 bb = sD[j];
      if (bb.x > tX1 || bb.z < tX0 || bb.y > tY1 || bb.w < tY0) continue;
      float4 A = sA[j];
      float4 B = sB[j];
      float4 Z = sZ[j];
      float bx = cx - A.x, by = cy - A.y;
      float w0 = (A.z * bx + A.w * by) * B.z;
      float w1 = (B.x * bx + B.y * by) * B.z;
      float w2 = 1.0f - w0 - w1;
      float depth = (w0 * B.w + w1 * Z.x) + w2 * Z.y;
      bool ok = (w0 >= 0.0f) && (w1 >= 0.0f) && (w2 >= 0.0f) && (depth > 0.0f);
      float d = ok ? depth : BIGF;
      if (d < bestd) { bestd = d; bestf = base + j; }
    }
    __syncthreads();
  }
  emit_pixel(out, vb, colors, faces, n, V, C, bestf, cx, cy, row, col);
}

extern "C" void kernel_launch(void* const* d_in, const int* in_sizes, int n_in,
                              void* d_out, int out_size, void* d_ws, size_t ws_size,
                              hipStream_t stream) {
  const float* verts = (const float*)d_in[0];
  const float* colors = (const float*)d_in[1];
  const int* faces = (const int*)d_in[2];
  float* out = (float*)d_out;
  long long s0 = in_sizes[0], s1 = in_sizes[1], s2 = in_sizes[2];
  int C = (int)((3LL * s1) / s0);
  if (C < 1) C = 1;
  int NC = out_size / (HPIX * WPIX);
  int N = NC / C;
  if (N < 1) N = 1;
  int V = (int)(s0 / (3LL * N));
  int F = (int)(s2 / 3);

  // sorted-path ws layout: srecs | keys | hist | cursors | covmask | bins
  size_t offS = 0;
  size_t szS = (size_t)N * F * 4 * sizeof(float4);
  size_t offK = (offS + szS + 255) & ~(size_t)255;
  size_t szK = (size_t)N * F * sizeof(unsigned int);
  size_t offH = (offK + szK + 255) & ~(size_t)255;
  size_t szH = (size_t)N * NBUCK * sizeof(unsigned int);
  size_t offC2 = (offH + szH + 255) & ~(size_t)255;
  size_t szC2 = (size_t)N * NTILE * sizeof(unsigned int);
  size_t offCV = (offC2 + szC2 + 255) & ~(size_t)255;
  size_t szCV = (size_t)N * NTILE * 16 * sizeof(unsigned int);
  size_t offB2 = (offCV + szCV + 255) & ~(size_t)255;
  size_t szB2 = (size_t)N * NTILE * (size_t)F * sizeof(unsigned int);
  size_t need_sorted = offB2 + szB2;

  // fallback layout: recs | packed
  size_t szR = (size_t)N * F * 4 * sizeof(float4);
  size_t offP = (szR + 255) & ~(size_t)255;
  size_t szP = (size_t)N * HPIX * WPIX * sizeof(unsigned long long);

  dim3 block(TSX, TSY);
  char* ws = (char*)d_ws;
  int total = N * F;
  int npix = N * HPIX * WPIX;

  if (d_ws != nullptr && ws_size >= need_sorted) {
    float4* srecs = (float4*)(ws + offS);
    unsigned int* keys = (unsigned int*)(ws + offK);
    unsigned int* hist = (unsigned int*)(ws + offH);
    unsigned int* cursors = (unsigned int*)(ws + offC2);
    unsigned int* covmask = (unsigned int*)(ws + offCV);
    unsigned int* bins = (unsigned int*)(ws + offB2);
    hipMemsetAsync(hist, 0, szH, stream);
    key_hist_kernel<<<(total + 255) / 256, 256, 0, stream>>>(verts, faces, keys,
                                                             hist, V, F, N);
    scan_kernel<<<N, 1024, 0, stream>>>(hist);
    scatter_kernel<<<(total + 255) / 256, 256, 0, stream>>>(verts, faces, keys,
                                                            hist, srecs, V, F, N);
    bin_kernel<<<dim3(NTILE, N), 256, 0, stream>>>(srecs, cursors, bins,
                                                   covmask, F);
    raster_sorted<<<dim3(NTILE * 4, N), 512, 0, stream>>>(srecs, bins, cursors,
                                                          covmask, verts, colors,
                                                          faces, out, V, F, C);
  } else if (d_ws != nullptr && ws_size >= offP + szP) {
    float4* recs = (float4*)ws;
    unsigned long long* packed = (unsigned long long*)(ws + offP);
    init_kernel<<<(npix + 255) / 256, 256, 0, stream>>>(packed, npix);
    prep_kernel<<<(total + 255) / 256, 256, 0, stream>>>(verts, faces, recs, V, F, N);
    raster_seg<<<dim3(16, 16, N * SEG_FLAT), block, 0, stream>>>(recs, packed, F);
    resolve_kernel<<<(npix + 255) / 256, 256, 0, stream>>>(packed, verts, colors,
                                                           faces, out, V, F, C, N);
  } else {
    raster_l<<<dim3(16, 16, N), block, 0, stream>>>(verts, colors, faces, out,
                                                    V, F, C);
  }
}

// Round 11
// 165.334 us; speedup vs baseline: 1.8191x; 1.1745x over previous
//
#include <hip/hip_runtime.h>

#define HPIX 256
#define WPIX 256
#define TSX 16
#define TSY 16
#define NTILE 256            // 16x16 tiles of 16x16 px
#define FCH 256
#define SEG_FLAT 16          // segments over all faces (fallback path)
#define RSEG 8               // waves per quadrant block
#define CAP 6144             // LDS sort capacity (entries per tile bin)
#define NB2 1024             // per-tile depth-lb buckets
#define SENTU 0xFFFFFFFFu
#define BIGF 1000000000.0f
#define EPSF 1e-8f
#define MARGIN 0.125f
#define HP_SLOP 0.0625f      // >= 4x the FP eval error bound (~0.015 w-units)
#define EPSB 1e-3f           // break/prune slop >> corner-depth FP error (<1e-4 w/ WBOUND)
#define WBOUND 64.0f         // corner-|w| bound for tight lb FP error
#define INIT_PACK 0xFFFFFFFFFFFFFFFFull

struct FaceRec {
  float x2, y2, a0, b0, a1, b1, inv, z0, z1, z2;
  float xmin, ymin, xmax, ymax;
};

// Compute the per-face record with EXACTLY the reference's op order (no FMA).
__device__ __forceinline__ FaceRec make_rec(const float* __restrict__ vb,
                                            const int* __restrict__ faces, int f) {
#pragma clang fp contract(off)
  FaceRec r;
  int i0 = faces[f * 3 + 0], i1 = faces[f * 3 + 1], i2 = faces[f * 3 + 2];
  float x0 = vb[i0 * 3 + 0], y0 = vb[i0 * 3 + 1], z0 = vb[i0 * 3 + 2];
  float x1 = vb[i1 * 3 + 0], y1 = vb[i1 * 3 + 1], z1 = vb[i1 * 3 + 2];
  float x2 = vb[i2 * 3 + 0], y2 = vb[i2 * 3 + 1], z2 = vb[i2 * 3 + 2];
  float px0 = x0 / z0, py0 = y0 / z0;
  float px1 = x1 / z1, py1 = y1 / z1;
  float px2 = x2 / z2, py2 = y2 / z2;
  float a0 = py1 - py2, b0 = px2 - px1;   // (y1-y2), (x2-x1)
  float a1 = py2 - py0, b1 = px0 - px2;   // (y2-y0), (x0-x2)
  float dy02 = py0 - py2;
  float denom = a0 * b1 + b0 * dy02;      // (y1-y2)*(x0-x2) + (x2-x1)*(y0-y2)
  bool nz = fabsf(denom) > EPSF;
  bool valid = nz && (z0 > 0.0f) && (z1 > 0.0f) && (z2 > 0.0f);
  r.x2 = px2; r.y2 = py2; r.a0 = a0; r.b0 = b0; r.a1 = a1; r.b1 = b1;
  r.inv = valid ? 1.0f / denom : 0.0f;
  r.z0 = z0; r.z1 = z1;
  r.z2 = valid ? z2 : -1.0f;              // invalid -> depth<0 -> fails depth>0
  if (valid) {
    r.xmin = fminf(px0, fminf(px1, px2)) - MARGIN;
    r.xmax = fmaxf(px0, fmaxf(px1, px2)) + MARGIN;
    r.ymin = fminf(py0, fminf(py1, py2)) - MARGIN;
    r.ymax = fmaxf(py0, fmaxf(py1, py2)) + MARGIN;
  } else {
    r.xmin = 2.0f * BIGF; r.xmax = -2.0f * BIGF;
    r.ymin = 2.0f * BIGF; r.ymax = -2.0f * BIGF;
  }
  return r;
}

// prep: face-order records (coalesced writes; face id == record index).
__global__ void prep_kernel(const float* __restrict__ verts,
                            const int* __restrict__ faces,
                            float4* __restrict__ recs, int V, int F, int NIMG) {
  int idx = blockIdx.x * blockDim.x + threadIdx.x;
  int total = NIMG * F;
  if (idx >= total) return;
  int n = idx / F, f = idx - n * F;
  FaceRec r = make_rec(verts + (size_t)n * V * 3, faces, f);
  float4* o = recs + (size_t)idx * 4;
  o[0] = make_float4(r.x2, r.y2, r.a0, r.b0);
  o[1] = make_float4(r.a1, r.b1, r.inv, r.z0);
  o[2] = make_float4(r.z1, r.z2, 0.0f, 0.0f);
  o[3] = make_float4(r.xmin, r.ymin, r.xmax, r.ymax);
}

// Per (tile,image): stream faces, keep = bbox overlap + conservative corner
// half-plane; compute lb = min corner depth (depth is AFFINE in x,y -> min
// over tile rectangle is at a corner; valid lower bound for every pixel).
// Counting-sort kept entries by quantized lb in LDS, write coalesced.
// Also: register-accumulated coverage mask (round-10 technique).
__global__ __launch_bounds__(256) void bin_sort_kernel(
    const float4* __restrict__ recs, unsigned int* __restrict__ cursors,
    unsigned int* __restrict__ bins, unsigned int* __restrict__ covmask,
    int F, int FP) {
#pragma clang fp contract(off)
  const int t = blockIdx.x, n = blockIdx.y;
  const int tlx = t & 15, tly = t >> 4;
  const float X0 = (float)(tlx * TSX), X1 = X0 + (float)(TSX - 1);
  const float Y0 = (float)(tly * TSY), Y1 = Y0 + (float)(TSY - 1);
  __shared__ unsigned int s_ent[CAP];
  __shared__ unsigned int s_out[CAP];
  __shared__ unsigned int s_hist[NB2];
  __shared__ unsigned int s_scan[256];
  __shared__ unsigned int s_cnt[4];
  __shared__ unsigned int s_cur;
  __shared__ unsigned long long s_wcov[4][4];
  const int tid = (int)threadIdx.x;
  const int lane = tid & 63, wid = tid >> 6;
  if (tid == 0) s_cur = 0u;
  for (int i = tid; i < NB2; i += 256) s_hist[i] = 0u;
  __syncthreads();
  const float4* rb = recs + (size_t)n * F * 4;
  unsigned int* bin = bins + (size_t)(n * NTILE + t) * FP;
  unsigned long long cov[4] = {0ull, 0ull, 0ull, 0ull};
  for (int base = 0; base < F; base += 256) {
    int j = base + tid;
    bool keep = false;
    unsigned int e = 0u;
    if (j < F) {
      float4 D = rb[j * 4 + 3];
      keep = (D.x <= X1) && (D.z >= X0) && (D.y <= Y1) && (D.w >= Y0);
      if (keep) {
        float4 A = rb[j * 4 + 0];
        float4 B = rb[j * 4 + 1];
        float4 Z = rb[j * 4 + 2];
        float inv = B.z;
        float lb = -3.0e38f;               // slivers/invalid: sort first, test always
        if (fabsf(inv) <= 1.0f) {
          float m0 = -3.0e38f, m1 = -3.0e38f, m2 = -3.0e38f;
          float g = 0.0f, dmin = 3.0e38f;
#pragma unroll
          for (int c = 0; c < 4; ++c) {
            float ccx = (c & 1) ? X1 : X0;
            float ccy = (c & 2) ? Y1 : Y0;
            float bx = ccx - A.x, by = ccy - A.y;
            float w0 = (A.z * bx + A.w * by) * inv;
            float w1 = (B.x * bx + B.y * by) * inv;
            float w2 = 1.0f - w0 - w1;
            float dc = (w0 * B.w + w1 * Z.x) + w2 * Z.y;
            m0 = fmaxf(m0, w0); m1 = fmaxf(m1, w1); m2 = fmaxf(m2, w2);
            g = fmaxf(g, fmaxf(fabsf(w0), fmaxf(fabsf(w1), fabsf(w2))));
            dmin = fminf(dmin, dc);
          }
          keep = (m0 >= -HP_SLOP) && (m1 >= -HP_SLOP) && (m2 >= -HP_SLOP);
          lb = (g <= WBOUND) ? dmin : -3.0e38f;  // huge-w: FP bound too loose
        }
        if (keep) {
          int bq = (lb <= 1.0f) ? 0 : (int)floorf((lb - 1.0f) * (float)NB2);
          bq = bq < 0 ? 0 : (bq > NB2 - 1 ? NB2 - 1 : bq);
          e = ((unsigned int)bq << 16) | (unsigned int)j;
          atomicAdd(&s_hist[bq], 1u);
          // coverage rectangle into registers (no LDS atomics -- r9 lesson)
          int cmin = (int)ceilf(D.x - X0);  cmin = cmin < 0 ? 0 : cmin;
          int cmax = (int)floorf(D.z - X0); cmax = cmax > 15 ? 15 : cmax;
          int rmin = (int)ceilf(D.y - Y0);  rmin = rmin < 0 ? 0 : rmin;
          int rmax = (int)floorf(D.w - Y0); rmax = rmax > 15 ? 15 : rmax;
          if (cmin <= cmax && rmin <= rmax) {
            unsigned int colm = (0xFFFFu << cmin) & (0xFFFFu >> (15 - cmax));
            unsigned int rowm = (0xFFFFu << rmin) & (0xFFFFu >> (15 - rmax));
            unsigned long long rep =
                (unsigned long long)colm * 0x0001000100010001ull;
#pragma unroll
            for (int k = 0; k < 4; ++k) {
              unsigned int rm4 = (rowm >> (4 * k)) & 0xFu;
              unsigned long long mk =
                  ((rm4 & 1u) ? 0x000000000000FFFFull : 0ull) |
                  ((rm4 & 2u) ? 0x00000000FFFF0000ull : 0ull) |
                  ((rm4 & 4u) ? 0x0000FFFF00000000ull : 0ull) |
                  ((rm4 & 8u) ? 0xFFFF000000000000ull : 0ull);
              cov[k] |= rep & mk;
            }
          }
        }
      }
    }
    unsigned long long m = __ballot(keep);
    int cw = __popcll(m);
    if (lane == 0) s_cnt[wid] = (unsigned int)cw;
    __syncthreads();
    unsigned int woff = s_cur;
    for (int w = 0; w < wid; ++w) woff += s_cnt[w];
    unsigned int tot = s_cnt[0] + s_cnt[1] + s_cnt[2] + s_cnt[3];
    if (keep) {
      unsigned int pos = woff + (unsigned int)__popcll(m & ((1ull << lane) - 1ull));
      if (pos < CAP) s_ent[pos] = e;
      else bin[pos] = e;                   // overflow: append unsorted
    }
    __syncthreads();
    if (tid == 0) s_cur += tot;
  }
  // coverage reduce (registers -> per-wave -> tile mask)
#pragma unroll
  for (int off = 1; off < 64; off <<= 1) {
#pragma unroll
    for (int k = 0; k < 4; ++k) cov[k] |= __shfl_xor(cov[k], off);
  }
  if (lane == 0) {
#pragma unroll
    for (int k = 0; k < 4; ++k) s_wcov[wid][k] = cov[k];
  }
  __syncthreads();                          // s_cur final, s_wcov ready
  unsigned int cnt = s_cur;
  if (tid < 16) {
    int r = tid, k = r >> 2, sh = (r & 3) * 16;
    unsigned int v = 0u;
#pragma unroll
    for (int w = 0; w < 4; ++w)
      v |= (unsigned int)((s_wcov[w][k] >> sh) & 0xFFFFull);
    covmask[(size_t)(n * NTILE + t) * 16 + r] = v;
  }
  bool sorted = (cnt <= CAP);
  if (sorted) {
    // exclusive scan of 1024-bucket hist (4 per thread + Hillis-Steele)
    unsigned int v0 = s_hist[4 * tid], v1 = s_hist[4 * tid + 1];
    unsigned int v2 = s_hist[4 * tid + 2], v3 = s_hist[4 * tid + 3];
    unsigned int sum = v0 + v1 + v2 + v3;
    s_scan[tid] = sum;
    __syncthreads();
    for (int off = 1; off < 256; off <<= 1) {
      unsigned int x = (tid >= off) ? s_scan[tid - off] : 0u;
      __syncthreads();
      s_scan[tid] += x;
      __syncthreads();
    }
    unsigned int excl = s_scan[tid] - sum;
    s_hist[4 * tid] = excl;
    s_hist[4 * tid + 1] = excl + v0;
    s_hist[4 * tid + 2] = excl + v0 + v1;
    s_hist[4 * tid + 3] = excl + v0 + v1 + v2;
    __syncthreads();
    for (int i = tid; i < (int)cnt; i += 256) {
      unsigned int e = s_ent[i];
      unsigned int b = e >> 16;
      unsigned int pos = atomicAdd(&s_hist[b], 1u);
      s_out[pos] = e;                       // within-bucket order arbitrary: OK,
    }                                       // u64-min result is order-independent
    __syncthreads();
    for (int i = tid; i < (int)cnt; i += 256) bin[i] = s_out[i];
  } else {
    for (int i = tid; i < CAP; i += 256) bin[i] = s_ent[i];
  }
  if (tid < 64) bin[cnt + (unsigned int)tid] = SENTU;   // sentinel pad
  if (tid == 0)
    cursors[n * NTILE + t] = cnt | (sorted ? 0x80000000u : 0u);
}

// Epilogue: interpolate colors for the winning face, apply any-positive mask,
// write NCHW. Recomputes weights via make_rec -> bit-identical values.
__device__ __forceinline__ void emit_pixel(float* __restrict__ out,
    const float* __restrict__ vb, const float* __restrict__ colors,
    const int* __restrict__ faces, int n, int V, int C, int bestf,
    float cx, float cy, int row, int col) {
#pragma clang fp contract(off)
  float cv[8];
#pragma unroll
  for (int ch = 0; ch < 8; ++ch) cv[ch] = 0.0f;
  if (bestf >= 0) {
    int i0 = faces[bestf * 3 + 0], i1 = faces[bestf * 3 + 1], i2 = faces[bestf * 3 + 2];
    FaceRec r = make_rec(vb, faces, bestf);
    float bx = cx - r.x2, by = cy - r.y2;
    float w0 = (r.a0 * bx + r.b0 * by) * r.inv;
    float w1 = (r.a1 * bx + r.b1 * by) * r.inv;
    float w2 = 1.0f - w0 - w1;
    const float* c0 = colors + ((size_t)n * V + i0) * C;
    const float* c1 = colors + ((size_t)n * V + i1) * C;
    const float* c2 = colors + ((size_t)n * V + i2) * C;
    for (int ch = 0; ch < C && ch < 8; ++ch)
      cv[ch] = (w0 * c0[ch] + w1 * c1[ch]) + w2 * c2[ch];
  }
  bool anyp = false;
  for (int ch = 0; ch < C && ch < 8; ++ch) anyp = anyp || (cv[ch] > 0.0f);
  float m = anyp ? 1.0f : 0.0f;
  size_t base = (size_t)n * C * HPIX * WPIX + (size_t)row * WPIX + col;
  for (int ch = 0; ch < C && ch < 8; ++ch)
    out[base + (size_t)ch * HPIX * WPIX] = cv[ch] * m;
}

#define TESTJ(Ak, Bk, Zk, jk)                                                 \
  {                                                                           \
    float bx = cx - Ak.x, by = cy - Ak.y;                                     \
    float w0 = (Ak.z * bx + Ak.w * by) * Bk.z;                                \
    float w1 = (Bk.x * bx + Bk.y * by) * Bk.z;                                \
    float w2 = 1.0f - w0 - w1;                                                \
    float depth = (w0 * Bk.w + w1 * Zk.x) + w2 * Zk.y;                        \
    bool ok = (w0 >= 0.0f) && (w1 >= 0.0f) && (w2 >= 0.0f) && (depth > 0.0f); \
    if (ok) {                                                                 \
      unsigned long long p =                                                  \
          ((unsigned long long)__float_as_uint(depth) << 32) | (unsigned)(jk);\
      if (p < best) best = p;                                                 \
    }                                                                         \
  }

// 8 waves per 8x8 quadrant; wave w scans batches {4w, 4w+32, ...} of the
// lb-sorted bin (bucket-ascending). Break when all covered lanes' shared
// depth cut beats the batch's bucket lower edge (later entries have lb >=
// that edge => depth > dcut strictly => can't win or tie). Per-entry gate:
// lane needs the test only if pixel in bbox AND entry lb <= dcut+EPSB --
// makes candidate-less border lanes skim the bin cheaply.
__global__ __launch_bounds__(512) void raster_sorted(
    const float4* __restrict__ recs, const unsigned int* __restrict__ bins,
    const unsigned int* __restrict__ cursors,
    const unsigned int* __restrict__ covmask,
    const float* __restrict__ verts, const float* __restrict__ colors,
    const int* __restrict__ faces, float* __restrict__ out,
    int V, int F, int FP, int C) {
#pragma clang fp contract(off)
  __shared__ unsigned long long sdmin[64];
  const int bq = blockIdx.x;
  const int t = bq >> 2, quad = bq & 3;
  const int n = blockIdx.y;
  const int tlx = t & 15, tly = t >> 4;
  const int tid = (int)threadIdx.x;
  const int wave = tid >> 6, lane = tid & 63;
  const int tx = lane & 7, ty = lane >> 3;
  const int cloc = (quad & 1) * 8 + tx, rloc = (quad >> 1) * 8 + ty;
  const int col = tlx * TSX + cloc, row = tly * TSY + rloc;
  const float cx = (float)col, cy = (float)row;
  const float4* rb = recs + (size_t)n * F * 4;
  const unsigned int* bin = bins + (size_t)(n * NTILE + t) * FP;
  const unsigned int cw = cursors[n * NTILE + t];
  const int cnt = (int)(cw & 0x7FFFFFFFu);
  const bool sorted = (cw & 0x80000000u) != 0u;
  const bool covered =
      (covmask[(size_t)(n * NTILE + t) * 16 + rloc] >> cloc) & 1u;
  if (tid < 64) sdmin[tid] = INIT_PACK;
  __syncthreads();
  unsigned long long best = INIT_PACK;
  if (covered) {
    unsigned long long written = INIT_PACK;
    const int stride = RSEG * 4;
    uint4 E = make_uint4(SENTU, SENTU, SENTU, SENTU);
    int i0 = wave * 4;
    if (i0 < cnt) E = *(const uint4*)(bin + i0);
    for (; i0 < cnt; i0 += stride) {
      int ni = i0 + stride;
      uint4 NE = make_uint4(SENTU, SENTU, SENTU, SENTU);
      if (ni < cnt) NE = *(const uint4*)(bin + ni);
      unsigned long long sh = sdmin[lane];
      float dcut = __uint_as_float((unsigned int)(sh >> 32));  // NaN if INIT
      unsigned int b0 = E.x >> 16;
      float lower0 = (b0 == 0u) ? -3.0e38f
                                : 1.0f + (float)b0 * (1.0f / (float)NB2);
      if (sorted && __all(lower0 > dcut + EPSB)) break;
#define PROCE(ek)                                                             \
      if (ek != SENTU) {                                                      \
        int j = (int)(ek & 0xFFFFu);                                          \
        unsigned int bk = ek >> 16;                                           \
        float lw = (bk == 0u) ? -3.0e38f                                      \
                              : 1.0f + (float)bk * (1.0f / (float)NB2);       \
        float4 D = rb[j * 4 + 3];                                             \
        bool live = (cx >= D.x) && (cx <= D.z) && (cy >= D.y) && (cy <= D.w)  \
                    && !(lw > dcut + EPSB);                                   \
        if (__any(live)) {                                                    \
          float4 A = rb[j * 4 + 0];                                           \
          float4 B = rb[j * 4 + 1];                                           \
          float4 Z = rb[j * 4 + 2];                                           \
          TESTJ(A, B, Z, j);                                                  \
        }                                                                     \
      }
      PROCE(E.x) PROCE(E.y) PROCE(E.z) PROCE(E.w)
#undef PROCE
      if (best < written) { atomicMin(&sdmin[lane], best); written = best; }
      E = NE;
    }
    if (best < written) atomicMin(&sdmin[lane], best);
  }
  __syncthreads();
  if (tid < 64) {
    unsigned long long b = sdmin[lane];
    int bestf = (b == INIT_PACK) ? -1 : (int)(unsigned int)(b & 0xFFFFFFFFull);
    emit_pixel(out, verts + (size_t)n * V * 3, colors, faces, n, V, C, bestf,
               cx, cy, row, col);
  }
}

// ---------- fallbacks (smaller ws or F >= 65536) ----------
__global__ void init_kernel(unsigned long long* __restrict__ packed, int npix) {
  int i = blockIdx.x * blockDim.x + threadIdx.x;
  if (i < npix) packed[i] = INIT_PACK;
}

__device__ __forceinline__ void test_face(float4 A, float4 B, float4 Z, int f,
                                          float cx, float cy,
                                          unsigned long long& best) {
#pragma clang fp contract(off)
  float bx = cx - A.x, by = cy - A.y;
  float w0 = (A.z * bx + A.w * by) * B.z;
  float w1 = (B.x * bx + B.y * by) * B.z;
  float w2 = 1.0f - w0 - w1;
  float depth = (w0 * B.w + w1 * Z.x) + w2 * Z.y;
  bool ok = (w0 >= 0.0f) && (w1 >= 0.0f) && (w2 >= 0.0f) && (depth > 0.0f);
  if (ok) {
    unsigned long long p =
        ((unsigned long long)__float_as_uint(depth) << 32) | (unsigned int)f;
    best = p < best ? p : best;
  }
}

__global__ __launch_bounds__(256) void raster_seg(
    const float4* __restrict__ recs, unsigned long long* __restrict__ packed,
    int F) {
  const int tx = threadIdx.x, ty = threadIdx.y;
  const int n = blockIdx.z / SEG_FLAT, s = blockIdx.z % SEG_FLAT;
  const int col = blockIdx.x * TSX + tx, row = blockIdx.y * TSY + ty;
  const float cx = (float)col, cy = (float)row;
  const float tX0 = (float)(blockIdx.x * TSX), tX1 = tX0 + (float)(TSX - 1);
  const float tY0 = (float)(blockIdx.y * TSY), tY1 = tY0 + (float)(TSY - 1);
  const float4* rb = recs + (size_t)n * F * 4;
  unsigned long long best = INIT_PACK;
  for (int f = s; f < F; f += SEG_FLAT) {
    float4 bb = rb[f * 4 + 3];
    if (bb.x > tX1 || bb.z < tX0 || bb.y > tY1 || bb.w < tY0) continue;
    float4 A = rb[f * 4 + 0];
    float4 B = rb[f * 4 + 1];
    float4 Z = rb[f * 4 + 2];
    test_face(A, B, Z, f, cx, cy, best);
  }
  if (best != INIT_PACK)
    atomicMin(&packed[(size_t)n * (HPIX * WPIX) + row * WPIX + col], best);
}

__global__ __launch_bounds__(256) void resolve_kernel(
    const unsigned long long* __restrict__ packed,
    const float* __restrict__ verts, const float* __restrict__ colors,
    const int* __restrict__ faces, float* __restrict__ out,
    int V, int F, int C, int NIMG) {
  int i = blockIdx.x * blockDim.x + threadIdx.x;
  int total = NIMG * HPIX * WPIX;
  if (i >= total) return;
  int n = i / (HPIX * WPIX);
  int pix = i - n * (HPIX * WPIX);
  int row = pix >> 8, col = pix & 255;
  unsigned long long p = packed[i];
  int bestf = (p == INIT_PACK) ? -1 : (int)(unsigned int)(p & 0xFFFFFFFFull);
  emit_pixel(out, verts + (size_t)n * V * 3, colors, faces, n, V, C, bestf,
             (float)col, (float)row, row, col);
}

__global__ __launch_bounds__(256) void raster_l(const float* __restrict__ verts,
    const float* __restrict__ colors, const int* __restrict__ faces,
    float* __restrict__ out, int V, int F, int C) {
#pragma clang fp contract(off)
  __shared__ float4 sA[FCH], sB[FCH], sZ[FCH], sD[FCH];
  const int n = blockIdx.z;
  const int tx = threadIdx.x, ty = threadIdx.y;
  const int tid = ty * TSX + tx;
  const int col = blockIdx.x * TSX + tx;
  const int row = blockIdx.y * TSY + ty;
  const float cx = (float)col, cy = (float)row;
  const float tX0 = (float)(blockIdx.x * TSX), tX1 = tX0 + (float)(TSX - 1);
  const float tY0 = (float)(blockIdx.y * TSY), tY1 = tY0 + (float)(TSY - 1);
  const float* vb = verts + (size_t)n * V * 3;
  float bestd = BIGF;
  int bestf = -1;
  for (int base = 0; base < F; base += FCH) {
    int cnt = min(FCH, F - base);
    if (tid < cnt) {
      FaceRec r = make_rec(vb, faces, base + tid);
      sA[tid] = make_float4(r.x2, r.y2, r.a0, r.b0);
      sB[tid] = make_float4(r.a1, r.b1, r.inv, r.z0);
      sZ[tid] = make_float4(r.z1, r.z2, 0.0f, 0.0f);
      sD[tid] = make_float4(r.xmin, r.ymin, r.xmax, r.ymax);
    }
    __syncthreads();
    for (int j = 0; j < cnt; ++j) {
      float4 bb = sD[j];
      if (bb.x > tX1 || bb.z < tX0 || bb.y > tY1 || bb.w < tY0) continue;
      float4 A = sA[j];
      float4 B = sB[j];
      float4 Z = sZ[j];
      float bx = cx - A.x, by = cy - A.y;
      float w0 = (A.z * bx + A.w * by) * B.z;
      float w1 = (B.x * bx + B.y * by) * B.z;
      float w2 = 1.0f - w0 - w1;
      float depth = (w0 * B.w + w1 * Z.x) + w2 * Z.y;
      bool ok = (w0 >= 0.0f) && (w1 >= 0.0f) && (w2 >= 0.0f) && (depth > 0.0f);
      float d = ok ? depth : BIGF;
      if (d < bestd) { bestd = d; bestf = base + j; }
    }
    __syncthreads();
  }
  emit_pixel(out, vb, colors, faces, n, V, C, bestf, cx, cy, row, col);
}

extern "C" void kernel_launch(void* const* d_in, const int* in_sizes, int n_in,
                              void* d_out, int out_size, void* d_ws, size_t ws_size,
                              hipStream_t stream) {
  const float* verts = (const float*)d_in[0];
  const float* colors = (const float*)d_in[1];
  const int* faces = (const int*)d_in[2];
  float* out = (float*)d_out;
  long long s0 = in_sizes[0], s1 = in_sizes[1], s2 = in_sizes[2];
  int C = (int)((3LL * s1) / s0);
  if (C < 1) C = 1;
  int NC = out_size / (HPIX * WPIX);
  int N = NC / C;
  if (N < 1) N = 1;
  int V = (int)(s0 / (3LL * N));
  int F = (int)(s2 / 3);
  int FP = (F + 64 + 3) & ~3;              // bin stride: cnt+64 sentinels, 16B aligned

  // sorted-path ws layout: recs | cursors | covmask | bins
  size_t offS = 0;
  size_t szS = (size_t)N * F * 4 * sizeof(float4);
  size_t offC2 = (offS + szS + 255) & ~(size_t)255;
  size_t szC2 = (size_t)N * NTILE * sizeof(unsigned int);
  size_t offCV = (offC2 + szC2 + 255) & ~(size_t)255;
  size_t szCV = (size_t)N * NTILE * 16 * sizeof(unsigned int);
  size_t offB2 = (offCV + szCV + 255) & ~(size_t)255;
  size_t szB2 = (size_t)N * NTILE * (size_t)FP * sizeof(unsigned int);
  size_t need_sorted = offB2 + szB2;

  // fallback layout: recs | packed
  size_t szR = (size_t)N * F * 4 * sizeof(float4);
  size_t offP = (szR + 255) & ~(size_t)255;
  size_t szP = (size_t)N * HPIX * WPIX * sizeof(unsigned long long);

  dim3 block(TSX, TSY);
  char* ws = (char*)d_ws;
  int total = N * F;
  int npix = N * HPIX * WPIX;

  if (d_ws != nullptr && ws_size >= need_sorted && F < 65536) {
    float4* recs = (float4*)(ws + offS);
    unsigned int* cursors = (unsigned int*)(ws + offC2);
    unsigned int* covmask = (unsigned int*)(ws + offCV);
    unsigned int* bins = (unsigned int*)(ws + offB2);
    prep_kernel<<<(total + 255) / 256, 256, 0, stream>>>(verts, faces, recs,
                                                         V, F, N);
    bin_sort_kernel<<<dim3(NTILE, N), 256, 0, stream>>>(recs, cursors, bins,
                                                        covmask, F, FP);
    raster_sorted<<<dim3(NTILE * 4, N), 512, 0, stream>>>(recs, bins, cursors,
                                                          covmask, verts, colors,
                                                          faces, out, V, F, FP, C);
  } else if (d_ws != nullptr && ws_size >= offP + szP) {
    float4* recs = (float4*)ws;
    unsigned long long* packed = (unsigned long long*)(ws + offP);
    init_kernel<<<(npix + 255) / 256, 256, 0, stream>>>(packed, npix);
    prep_kernel<<<(total + 255) / 256, 256, 0, stream>>>(verts, faces, recs, V, F, N);
    raster_seg<<<dim3(16, 16, N * SEG_FLAT), block, 0, stream>>>(recs, packed, F);
    resolve_kernel<<<(npix + 255) / 256, 256, 0, stream>>>(packed, verts, colors,
                                                           faces, out, V, F, C, N);
  } else {
    raster_l<<<dim3(16, 16, N), block, 0, stream>>>(verts, colors, faces, out,
                                                    V, F, C);
  }
}

// Round 12
// 148.516 us; speedup vs baseline: 2.0251x; 1.1132x over previous
//
#include <hip/hip_runtime.h>

#define HPIX 256
#define WPIX 256
#define TSX 16
#define TSY 16
#define NTILE 256            // 16x16 tiles of 16x16 px
#define FCH 256
#define SEG_FLAT 16          // segments over all faces (fallback path)
#define RSEG 8               // waves per quadrant block (raster)
#define CAP 6144             // LDS sort capacity (entries per tile bin)
#define NB2 1024             // per-tile depth-lb buckets
#define SENTU 0xFFFFFFFFu
#define BIGF 1000000000.0f
#define EPSF 1e-8f
#define MARGIN 0.125f
#define HP_SLOP 0.0625f      // >= 4x the FP eval error bound (~0.015 w-units)
#define EPSB 1e-3f           // break/prune slop >> corner-depth FP error (<1e-4 w/ WBOUND)
#define WBOUND 64.0f         // corner-|w| bound for tight lb FP error
#define INIT_PACK 0xFFFFFFFFFFFFFFFFull

struct FaceRec {
  float x2, y2, a0, b0, a1, b1, inv, z0, z1, z2;
  float xmin, ymin, xmax, ymax;
};

// Compute the per-face record with EXACTLY the reference's op order (no FMA).
__device__ __forceinline__ FaceRec make_rec(const float* __restrict__ vb,
                                            const int* __restrict__ faces, int f) {
#pragma clang fp contract(off)
  FaceRec r;
  int i0 = faces[f * 3 + 0], i1 = faces[f * 3 + 1], i2 = faces[f * 3 + 2];
  float x0 = vb[i0 * 3 + 0], y0 = vb[i0 * 3 + 1], z0 = vb[i0 * 3 + 2];
  float x1 = vb[i1 * 3 + 0], y1 = vb[i1 * 3 + 1], z1 = vb[i1 * 3 + 2];
  float x2 = vb[i2 * 3 + 0], y2 = vb[i2 * 3 + 1], z2 = vb[i2 * 3 + 2];
  float px0 = x0 / z0, py0 = y0 / z0;
  float px1 = x1 / z1, py1 = y1 / z1;
  float px2 = x2 / z2, py2 = y2 / z2;
  float a0 = py1 - py2, b0 = px2 - px1;   // (y1-y2), (x2-x1)
  float a1 = py2 - py0, b1 = px0 - px2;   // (y2-y0), (x0-x2)
  float dy02 = py0 - py2;
  float denom = a0 * b1 + b0 * dy02;      // (y1-y2)*(x0-x2) + (x2-x1)*(y0-y2)
  bool nz = fabsf(denom) > EPSF;
  bool valid = nz && (z0 > 0.0f) && (z1 > 0.0f) && (z2 > 0.0f);
  r.x2 = px2; r.y2 = py2; r.a0 = a0; r.b0 = b0; r.a1 = a1; r.b1 = b1;
  r.inv = valid ? 1.0f / denom : 0.0f;
  r.z0 = z0; r.z1 = z1;
  r.z2 = valid ? z2 : -1.0f;              // invalid -> depth<0 -> fails depth>0
  if (valid) {
    r.xmin = fminf(px0, fminf(px1, px2)) - MARGIN;
    r.xmax = fmaxf(px0, fmaxf(px1, px2)) + MARGIN;
    r.ymin = fminf(py0, fminf(py1, py2)) - MARGIN;
    r.ymax = fmaxf(py0, fmaxf(py1, py2)) + MARGIN;
  } else {
    r.xmin = 2.0f * BIGF; r.xmax = -2.0f * BIGF;
    r.ymin = 2.0f * BIGF; r.ymax = -2.0f * BIGF;
  }
  return r;
}

// prep (split layout): A,B,Z at 48B stride; bboxes dense 16B.
__global__ void prep_split(const float* __restrict__ verts,
                           const int* __restrict__ faces,
                           float4* __restrict__ abz, float4* __restrict__ dq,
                           int V, int F, int NIMG) {
  int idx = blockIdx.x * blockDim.x + threadIdx.x;
  if (idx >= NIMG * F) return;
  int n = idx / F, f = idx - n * F;
  FaceRec r = make_rec(verts + (size_t)n * V * 3, faces, f);
  float4* o = abz + (size_t)idx * 3;
  o[0] = make_float4(r.x2, r.y2, r.a0, r.b0);
  o[1] = make_float4(r.a1, r.b1, r.inv, r.z0);
  o[2] = make_float4(r.z1, r.z2, 0.0f, 0.0f);
  dq[idx] = make_float4(r.xmin, r.ymin, r.xmax, r.ymax);
}

// Per (tile,image), 512 threads: stream faces (dense bbox sieve), keep =
// bbox overlap + conservative corner half-plane; lb = min corner depth
// (depth affine in x,y -> tile min at a corner). Counting-sort kept entries
// by quantized lb: s_ent staging + direct scatter to global bin (no s_out --
// round-11 lesson: 48KB LDS capped occupancy at 20%).
__global__ __launch_bounds__(512) void bin_sort_kernel(
    const float4* __restrict__ abz_g, const float4* __restrict__ dq_g,
    unsigned int* __restrict__ cursors, unsigned int* __restrict__ bins,
    unsigned int* __restrict__ covmask, int F, int FP) {
#pragma clang fp contract(off)
  const int t = blockIdx.x, n = blockIdx.y;
  const int tlx = t & 15, tly = t >> 4;
  const float X0 = (float)(tlx * TSX), X1 = X0 + (float)(TSX - 1);
  const float Y0 = (float)(tly * TSY), Y1 = Y0 + (float)(TSY - 1);
  __shared__ unsigned int s_ent[CAP];
  __shared__ unsigned int s_hist[NB2];
  __shared__ unsigned int s_scan[256];
  __shared__ unsigned int s_cnt[8];
  __shared__ unsigned int s_cur;
  __shared__ unsigned long long s_wcov[8][4];
  const int tid = (int)threadIdx.x;
  const int lane = tid & 63, wid = tid >> 6;
  if (tid == 0) s_cur = 0u;
  for (int i = tid; i < NB2; i += 512) s_hist[i] = 0u;
  __syncthreads();
  const float4* abz = abz_g + (size_t)n * F * 3;
  const float4* dq = dq_g + (size_t)n * F;
  unsigned int* bin = bins + (size_t)(n * NTILE + t) * FP;
  unsigned long long cov[4] = {0ull, 0ull, 0ull, 0ull};
  for (int base = 0; base < F; base += 512) {
    int j = base + tid;
    bool keep = false;
    unsigned int e = 0u;
    if (j < F) {
      float4 D = dq[j];
      keep = (D.x <= X1) && (D.z >= X0) && (D.y <= Y1) && (D.w >= Y0);
      if (keep) {
        float4 A = abz[j * 3 + 0];
        float4 B = abz[j * 3 + 1];
        float4 Z = abz[j * 3 + 2];
        float inv = B.z;
        float lb = -3.0e38f;               // slivers/invalid: sort first, test always
        if (fabsf(inv) <= 1.0f) {
          float m0 = -3.0e38f, m1 = -3.0e38f, m2 = -3.0e38f;
          float g = 0.0f, dmin = 3.0e38f;
#pragma unroll
          for (int c = 0; c < 4; ++c) {
            float ccx = (c & 1) ? X1 : X0;
            float ccy = (c & 2) ? Y1 : Y0;
            float bx = ccx - A.x, by = ccy - A.y;
            float w0 = (A.z * bx + A.w * by) * inv;
            float w1 = (B.x * bx + B.y * by) * inv;
            float w2 = 1.0f - w0 - w1;
            float dc = (w0 * B.w + w1 * Z.x) + w2 * Z.y;
            m0 = fmaxf(m0, w0); m1 = fmaxf(m1, w1); m2 = fmaxf(m2, w2);
            g = fmaxf(g, fmaxf(fabsf(w0), fmaxf(fabsf(w1), fabsf(w2))));
            dmin = fminf(dmin, dc);
          }
          keep = (m0 >= -HP_SLOP) && (m1 >= -HP_SLOP) && (m2 >= -HP_SLOP);
          lb = (g <= WBOUND) ? dmin : -3.0e38f;  // huge-w: FP bound too loose
        }
        if (keep) {
          int bq = (lb <= 1.0f) ? 0 : (int)floorf((lb - 1.0f) * (float)NB2);
          bq = bq < 0 ? 0 : (bq > NB2 - 1 ? NB2 - 1 : bq);
          e = ((unsigned int)bq << 16) | (unsigned int)j;
          atomicAdd(&s_hist[bq], 1u);
          // coverage rectangle into registers (no LDS atomics -- r9 lesson)
          int cmin = (int)ceilf(D.x - X0);  cmin = cmin < 0 ? 0 : cmin;
          int cmax = (int)floorf(D.z - X0); cmax = cmax > 15 ? 15 : cmax;
          int rmin = (int)ceilf(D.y - Y0);  rmin = rmin < 0 ? 0 : rmin;
          int rmax = (int)floorf(D.w - Y0); rmax = rmax > 15 ? 15 : rmax;
          if (cmin <= cmax && rmin <= rmax) {
            unsigned int colm = (0xFFFFu << cmin) & (0xFFFFu >> (15 - cmax));
            unsigned int rowm = (0xFFFFu << rmin) & (0xFFFFu >> (15 - rmax));
            unsigned long long rep =
                (unsigned long long)colm * 0x0001000100010001ull;
#pragma unroll
            for (int k = 0; k < 4; ++k) {
              unsigned int rm4 = (rowm >> (4 * k)) & 0xFu;
              unsigned long long mk =
                  ((rm4 & 1u) ? 0x000000000000FFFFull : 0ull) |
                  ((rm4 & 2u) ? 0x00000000FFFF0000ull : 0ull) |
                  ((rm4 & 4u) ? 0x0000FFFF00000000ull : 0ull) |
                  ((rm4 & 8u) ? 0xFFFF000000000000ull : 0ull);
              cov[k] |= rep & mk;
            }
          }
        }
      }
    }
    unsigned long long m = __ballot(keep);
    int cw = __popcll(m);
    if (lane == 0) s_cnt[wid] = (unsigned int)cw;
    __syncthreads();
    unsigned int woff = s_cur;
    for (int w = 0; w < wid; ++w) woff += s_cnt[w];
    unsigned int tot = 0;
#pragma unroll
    for (int w = 0; w < 8; ++w) tot += s_cnt[w];
    if (keep) {
      unsigned int pos = woff + (unsigned int)__popcll(m & ((1ull << lane) - 1ull));
      if (pos < CAP) s_ent[pos] = e;
      else bin[pos] = e;                   // overflow: append unsorted
    }
    __syncthreads();
    if (tid == 0) s_cur += tot;
  }
  // coverage reduce (registers -> per-wave -> tile mask)
#pragma unroll
  for (int off = 1; off < 64; off <<= 1) {
#pragma unroll
    for (int k = 0; k < 4; ++k) cov[k] |= __shfl_xor(cov[k], off);
  }
  if (lane == 0) {
#pragma unroll
    for (int k = 0; k < 4; ++k) s_wcov[wid][k] = cov[k];
  }
  __syncthreads();                          // s_cur final, s_wcov ready
  unsigned int cnt = s_cur;
  if (tid < 16) {
    int r = tid, k = r >> 2, sh = (r & 3) * 16;
    unsigned int v = 0u;
#pragma unroll
    for (int w = 0; w < 8; ++w)
      v |= (unsigned int)((s_wcov[w][k] >> sh) & 0xFFFFull);
    covmask[(size_t)(n * NTILE + t) * 16 + r] = v;
  }
  bool sorted = (cnt <= CAP);
  if (sorted) {
    // exclusive scan of 1024-bucket hist: threads 0..255 own 4 buckets each
    unsigned int v0 = 0, v1 = 0, v2 = 0, v3 = 0, sum = 0;
    if (tid < 256) {
      v0 = s_hist[4 * tid]; v1 = s_hist[4 * tid + 1];
      v2 = s_hist[4 * tid + 2]; v3 = s_hist[4 * tid + 3];
      sum = v0 + v1 + v2 + v3;
      s_scan[tid] = sum;
    }
    __syncthreads();
    for (int off = 1; off < 256; off <<= 1) {
      unsigned int x = 0;
      if (tid < 256 && tid >= off) x = s_scan[tid - off];
      __syncthreads();
      if (tid < 256) s_scan[tid] += x;
      __syncthreads();
    }
    if (tid < 256) {
      unsigned int excl = s_scan[tid] - sum;
      s_hist[4 * tid] = excl;
      s_hist[4 * tid + 1] = excl + v0;
      s_hist[4 * tid + 2] = excl + v0 + v1;
      s_hist[4 * tid + 3] = excl + v0 + v1 + v2;
    }
    __syncthreads();
    for (int i = tid; i < (int)cnt; i += 512) {
      unsigned int e = s_ent[i];
      unsigned int pos = atomicAdd(&s_hist[e >> 16], 1u);
      bin[pos] = e;                         // within-bucket order arbitrary: OK,
    }                                       // u64-min result is order-independent
  } else {
    for (int i = tid; i < CAP; i += 512) bin[i] = s_ent[i];
  }
  if (tid < 64) bin[cnt + (unsigned int)tid] = SENTU;   // sentinel pad
  if (tid == 0)
    cursors[n * NTILE + t] = cnt | (sorted ? 0x80000000u : 0u);
}

// Epilogue: interpolate colors for the winning face, apply any-positive mask,
// write NCHW. Recomputes weights via make_rec -> bit-identical values.
__device__ __forceinline__ void emit_pixel(float* __restrict__ out,
    const float* __restrict__ vb, const float* __restrict__ colors,
    const int* __restrict__ faces, int n, int V, int C, int bestf,
    float cx, float cy, int row, int col) {
#pragma clang fp contract(off)
  float cv[8];
#pragma unroll
  for (int ch = 0; ch < 8; ++ch) cv[ch] = 0.0f;
  if (bestf >= 0) {
    int i0 = faces[bestf * 3 + 0], i1 = faces[bestf * 3 + 1], i2 = faces[bestf * 3 + 2];
    FaceRec r = make_rec(vb, faces, bestf);
    float bx = cx - r.x2, by = cy - r.y2;
    float w0 = (r.a0 * bx + r.b0 * by) * r.inv;
    float w1 = (r.a1 * bx + r.b1 * by) * r.inv;
    float w2 = 1.0f - w0 - w1;
    const float* c0 = colors + ((size_t)n * V + i0) * C;
    const float* c1 = colors + ((size_t)n * V + i1) * C;
    const float* c2 = colors + ((size_t)n * V + i2) * C;
    for (int ch = 0; ch < C && ch < 8; ++ch)
      cv[ch] = (w0 * c0[ch] + w1 * c1[ch]) + w2 * c2[ch];
  }
  bool anyp = false;
  for (int ch = 0; ch < C && ch < 8; ++ch) anyp = anyp || (cv[ch] > 0.0f);
  float m = anyp ? 1.0f : 0.0f;
  size_t base = (size_t)n * C * HPIX * WPIX + (size_t)row * WPIX + col;
  for (int ch = 0; ch < C && ch < 8; ++ch)
    out[base + (size_t)ch * HPIX * WPIX] = cv[ch] * m;
}

#define TESTJ(Ak, Bk, Zk, jk)                                                 \
  {                                                                           \
    float bx = cx - Ak.x, by = cy - Ak.y;                                     \
    float w0 = (Ak.z * bx + Ak.w * by) * Bk.z;                                \
    float w1 = (Bk.x * bx + Bk.y * by) * Bk.z;                                \
    float w2 = 1.0f - w0 - w1;                                                \
    float depth = (w0 * Bk.w + w1 * Zk.x) + w2 * Zk.y;                        \
    bool ok = (w0 >= 0.0f) && (w1 >= 0.0f) && (w2 >= 0.0f) && (depth > 0.0f); \
    if (ok) {                                                                 \
      unsigned long long p =                                                  \
          ((unsigned long long)__float_as_uint(depth) << 32) | (unsigned)(jk);\
      if (p < best) best = p;                                                 \
    }                                                                         \
  }

// 8 waves per 8x8 quadrant; wave w scans batches {4w, 4w+32, ...} of the
// lb-sorted bin (bucket-ascending). Break when all covered lanes' shared
// depth cut beats the batch's bucket lower edge. Per-entry gate: lane needs
// the test only if pixel in bbox AND entry lb <= dcut+EPSB.
__global__ __launch_bounds__(512) void raster_sorted(
    const float4* __restrict__ abz_g, const float4* __restrict__ dq_g,
    const unsigned int* __restrict__ bins,
    const unsigned int* __restrict__ cursors,
    const unsigned int* __restrict__ covmask,
    const float* __restrict__ verts, const float* __restrict__ colors,
    const int* __restrict__ faces, float* __restrict__ out,
    int V, int F, int FP, int C) {
#pragma clang fp contract(off)
  __shared__ unsigned long long sdmin[64];
  const int bq = blockIdx.x;
  const int t = bq >> 2, quad = bq & 3;
  const int n = blockIdx.y;
  const int tlx = t & 15, tly = t >> 4;
  const int tid = (int)threadIdx.x;
  const int wave = tid >> 6, lane = tid & 63;
  const int tx = lane & 7, ty = lane >> 3;
  const int cloc = (quad & 1) * 8 + tx, rloc = (quad >> 1) * 8 + ty;
  const int col = tlx * TSX + cloc, row = tly * TSY + rloc;
  const float cx = (float)col, cy = (float)row;
  const float4* abz = abz_g + (size_t)n * F * 3;
  const float4* dq = dq_g + (size_t)n * F;
  const unsigned int* bin = bins + (size_t)(n * NTILE + t) * FP;
  const unsigned int cw = cursors[n * NTILE + t];
  const int cnt = (int)(cw & 0x7FFFFFFFu);
  const bool sorted = (cw & 0x80000000u) != 0u;
  const bool covered =
      (covmask[(size_t)(n * NTILE + t) * 16 + rloc] >> cloc) & 1u;
  if (tid < 64) sdmin[tid] = INIT_PACK;
  __syncthreads();
  unsigned long long best = INIT_PACK;
  if (covered) {
    unsigned long long written = INIT_PACK;
    const int stride = RSEG * 4;
    uint4 E = make_uint4(SENTU, SENTU, SENTU, SENTU);
    int i0 = wave * 4;
    if (i0 < cnt) E = *(const uint4*)(bin + i0);
    for (; i0 < cnt; i0 += stride) {
      int ni = i0 + stride;
      uint4 NE = make_uint4(SENTU, SENTU, SENTU, SENTU);
      if (ni < cnt) NE = *(const uint4*)(bin + ni);
      unsigned long long sh = sdmin[lane];
      float dcut = __uint_as_float((unsigned int)(sh >> 32));  // NaN if INIT
      unsigned int b0 = E.x >> 16;
      float lower0 = (b0 == 0u) ? -3.0e38f
                                : 1.0f + (float)b0 * (1.0f / (float)NB2);
      if (sorted && __all(lower0 > dcut + EPSB)) break;
#define PROCE(ek)                                                             \
      if (ek != SENTU) {                                                      \
        int j = (int)(ek & 0xFFFFu);                                          \
        unsigned int bk = ek >> 16;                                           \
        float lw = (bk == 0u) ? -3.0e38f                                      \
                              : 1.0f + (float)bk * (1.0f / (float)NB2);       \
        float4 D = dq[j];                                                     \
        bool live = (cx >= D.x) && (cx <= D.z) && (cy >= D.y) && (cy <= D.w)  \
                    && !(lw > dcut + EPSB);                                   \
        if (__any(live)) {                                                    \
          float4 A = abz[j * 3 + 0];                                          \
          float4 B = abz[j * 3 + 1];                                          \
          float4 Z = abz[j * 3 + 2];                                          \
          TESTJ(A, B, Z, j);                                                  \
        }                                                                     \
      }
      PROCE(E.x) PROCE(E.y) PROCE(E.z) PROCE(E.w)
#undef PROCE
      if (best < written) { atomicMin(&sdmin[lane], best); written = best; }
      E = NE;
    }
    if (best < written) atomicMin(&sdmin[lane], best);
  }
  __syncthreads();
  if (tid < 64) {
    unsigned long long b = sdmin[lane];
    int bestf = (b == INIT_PACK) ? -1 : (int)(unsigned int)(b & 0xFFFFFFFFull);
    emit_pixel(out, verts + (size_t)n * V * 3, colors, faces, n, V, C, bestf,
               cx, cy, row, col);
  }
}

// ---------- fallbacks (smaller ws or F >= 65536) ----------
__global__ void prep_kernel(const float* __restrict__ verts,
                            const int* __restrict__ faces,
                            float4* __restrict__ recs, int V, int F, int NIMG) {
  int idx = blockIdx.x * blockDim.x + threadIdx.x;
  int total = NIMG * F;
  if (idx >= total) return;
  int n = idx / F, f = idx - n * F;
  FaceRec r = make_rec(verts + (size_t)n * V * 3, faces, f);
  float4* o = recs + (size_t)idx * 4;
  o[0] = make_float4(r.x2, r.y2, r.a0, r.b0);
  o[1] = make_float4(r.a1, r.b1, r.inv, r.z0);
  o[2] = make_float4(r.z1, r.z2, 0.0f, 0.0f);
  o[3] = make_float4(r.xmin, r.ymin, r.xmax, r.ymax);
}

__global__ void init_kernel(unsigned long long* __restrict__ packed, int npix) {
  int i = blockIdx.x * blockDim.x + threadIdx.x;
  if (i < npix) packed[i] = INIT_PACK;
}

__device__ __forceinline__ void test_face(float4 A, float4 B, float4 Z, int f,
                                          float cx, float cy,
                                          unsigned long long& best) {
#pragma clang fp contract(off)
  float bx = cx - A.x, by = cy - A.y;
  float w0 = (A.z * bx + A.w * by) * B.z;
  float w1 = (B.x * bx + B.y * by) * B.z;
  float w2 = 1.0f - w0 - w1;
  float depth = (w0 * B.w + w1 * Z.x) + w2 * Z.y;
  bool ok = (w0 >= 0.0f) && (w1 >= 0.0f) && (w2 >= 0.0f) && (depth > 0.0f);
  if (ok) {
    unsigned long long p =
        ((unsigned long long)__float_as_uint(depth) << 32) | (unsigned int)f;
    best = p < best ? p : best;
  }
}

__global__ __launch_bounds__(256) void raster_seg(
    const float4* __restrict__ recs, unsigned long long* __restrict__ packed,
    int F) {
  const int tx = threadIdx.x, ty = threadIdx.y;
  const int n = blockIdx.z / SEG_FLAT, s = blockIdx.z % SEG_FLAT;
  const int col = blockIdx.x * TSX + tx, row = blockIdx.y * TSY + ty;
  const float cx = (float)col, cy = (float)row;
  const float tX0 = (float)(blockIdx.x * TSX), tX1 = tX0 + (float)(TSX - 1);
  const float tY0 = (float)(blockIdx.y * TSY), tY1 = tY0 + (float)(TSY - 1);
  const float4* rb = recs + (size_t)n * F * 4;
  unsigned long long best = INIT_PACK;
  for (int f = s; f < F; f += SEG_FLAT) {
    float4 bb = rb[f * 4 + 3];
    if (bb.x > tX1 || bb.z < tX0 || bb.y > tY1 || bb.w < tY0) continue;
    float4 A = rb[f * 4 + 0];
    float4 B = rb[f * 4 + 1];
    float4 Z = rb[f * 4 + 2];
    test_face(A, B, Z, f, cx, cy, best);
  }
  if (best != INIT_PACK)
    atomicMin(&packed[(size_t)n * (HPIX * WPIX) + row * WPIX + col], best);
}

__global__ __launch_bounds__(256) void resolve_kernel(
    const unsigned long long* __restrict__ packed,
    const float* __restrict__ verts, const float* __restrict__ colors,
    const int* __restrict__ faces, float* __restrict__ out,
    int V, int F, int C, int NIMG) {
  int i = blockIdx.x * blockDim.x + threadIdx.x;
  int total = NIMG * HPIX * WPIX;
  if (i >= total) return;
  int n = i / (HPIX * WPIX);
  int pix = i - n * (HPIX * WPIX);
  int row = pix >> 8, col = pix & 255;
  unsigned long long p = packed[i];
  int bestf = (p == INIT_PACK) ? -1 : (int)(unsigned int)(p & 0xFFFFFFFFull);
  emit_pixel(out, verts + (size_t)n * V * 3, colors, faces, n, V, C, bestf,
             (float)col, (float)row, row, col);
}

__global__ __launch_bounds__(256) void raster_l(const float* __restrict__ verts,
    const float* __restrict__ colors, const int* __restrict__ faces,
    float* __restrict__ out, int V, int F, int C) {
#pragma clang fp contract(off)
  __shared__ float4 sA[FCH], sB[FCH], sZ[FCH], sD[FCH];
  const int n = blockIdx.z;
  const int tx = threadIdx.x, ty = threadIdx.y;
  const int tid = ty * TSX + tx;
  const int col = blockIdx.x * TSX + tx;
  const int row = blockIdx.y * TSY + ty;
  const float cx = (float)col, cy = (float)row;
  const float tX0 = (float)(blockIdx.x * TSX), tX1 = tX0 + (float)(TSX - 1);
  const float tY0 = (float)(blockIdx.y * TSY), tY1 = tY0 + (float)(TSY - 1);
  const float* vb = verts + (size_t)n * V * 3;
  float bestd = BIGF;
  int bestf = -1;
  for (int base = 0; base < F; base += FCH) {
    int cnt = min(FCH, F - base);
    if (tid < cnt) {
      FaceRec r = make_rec(vb, faces, base + tid);
      sA[tid] = make_float4(r.x2, r.y2, r.a0, r.b0);
      sB[tid] = make_float4(r.a1, r.b1, r.inv, r.z0);
      sZ[tid] = make_float4(r.z1, r.z2, 0.0f, 0.0f);
      sD[tid] = make_float4(r.xmin, r.ymin, r.xmax, r.ymax);
    }
    __syncthreads();
    for (int j = 0; j < cnt; ++j) {
      float4 bb = sD[j];
      if (bb.x > tX1 || bb.z < tX0 || bb.y > tY1 || bb.w < tY0) continue;
      float4 A = sA[j];
      float4 B = sB[j];
      float4 Z = sZ[j];
      float bx = cx - A.x, by = cy - A.y;
      float w0 = (A.z * bx + A.w * by) * B.z;
      float w1 = (B.x * bx + B.y * by) * B.z;
      float w2 = 1.0f - w0 - w1;
      float depth = (w0 * B.w + w1 * Z.x) + w2 * Z.y;
      bool ok = (w0 >= 0.0f) && (w1 >= 0.0f) && (w2 >= 0.0f) && (depth > 0.0f);
      float d = ok ? depth : BIGF;
      if (d < bestd) { bestd = d; bestf = base + j; }
    }
    __syncthreads();
  }
  emit_pixel(out, vb, colors, faces, n, V, C, bestf, cx, cy, row, col);
}

extern "C" void kernel_launch(void* const* d_in, const int* in_sizes, int n_in,
                              void* d_out, int out_size, void* d_ws, size_t ws_size,
                              hipStream_t stream) {
  const float* verts = (const float*)d_in[0];
  const float* colors = (const float*)d_in[1];
  const int* faces = (const int*)d_in[2];
  float* out = (float*)d_out;
  long long s0 = in_sizes[0], s1 = in_sizes[1], s2 = in_sizes[2];
  int C = (int)((3LL * s1) / s0);
  if (C < 1) C = 1;
  int NC = out_size / (HPIX * WPIX);
  int N = NC / C;
  if (N < 1) N = 1;
  int V = (int)(s0 / (3LL * N));
  int F = (int)(s2 / 3);
  int FP = (F + 64 + 3) & ~3;              // bin stride: cnt+64 sentinels, 16B aligned

  // sorted-path ws layout: abz | dq | cursors | covmask | bins
  size_t offA = 0;
  size_t szA = (size_t)N * F * 3 * sizeof(float4);
  size_t offD = (offA + szA + 255) & ~(size_t)255;
  size_t szD = (size_t)N * F * sizeof(float4);
  size_t offC2 = (offD + szD + 255) & ~(size_t)255;
  size_t szC2 = (size_t)N * NTILE * sizeof(unsigned int);
  size_t offCV = (offC2 + szC2 + 255) & ~(size_t)255;
  size_t szCV = (size_t)N * NTILE * 16 * sizeof(unsigned int);
  size_t offB2 = (offCV + szCV + 255) & ~(size_t)255;
  size_t szB2 = (size_t)N * NTILE * (size_t)FP * sizeof(unsigned int);
  size_t need_sorted = offB2 + szB2;

  // fallback layout: recs | packed
  size_t szR = (size_t)N * F * 4 * sizeof(float4);
  size_t offP = (szR + 255) & ~(size_t)255;
  size_t szP = (size_t)N * HPIX * WPIX * sizeof(unsigned long long);

  dim3 block(TSX, TSY);
  char* ws = (char*)d_ws;
  int total = N * F;
  int npix = N * HPIX * WPIX;

  if (d_ws != nullptr && ws_size >= need_sorted && F < 65536) {
    float4* abz = (float4*)(ws + offA);
    float4* dq = (float4*)(ws + offD);
    unsigned int* cursors = (unsigned int*)(ws + offC2);
    unsigned int* covmask = (unsigned int*)(ws + offCV);
    unsigned int* bins = (unsigned int*)(ws + offB2);
    prep_split<<<(total + 255) / 256, 256, 0, stream>>>(verts, faces, abz, dq,
                                                        V, F, N);
    bin_sort_kernel<<<dim3(NTILE, N), 512, 0, stream>>>(abz, dq, cursors, bins,
                                                        covmask, F, FP);
    raster_sorted<<<dim3(NTILE * 4, N), 512, 0, stream>>>(abz, dq, bins, cursors,
                                                          covmask, verts, colors,
                                                          faces, out, V, F, FP, C);
  } else if (d_ws != nullptr && ws_size >= offP + szP) {
    float4* recs = (float4*)ws;
    unsigned long long* packed = (unsigned long long*)(ws + offP);
    init_kernel<<<(npix + 255) / 256, 256, 0, stream>>>(packed, npix);
    prep_kernel<<<(total + 255) / 256, 256, 0, stream>>>(verts, faces, recs, V, F, N);
    raster_seg<<<dim3(16, 16, N * SEG_FLAT), block, 0, stream>>>(recs, packed, F);
    resolve_kernel<<<(npix + 255) / 256, 256, 0, stream>>>(packed, verts, colors,
                                                           faces, out, V, F, C, N);
  } else {
    raster_l<<<dim3(16, 16, N), block, 0, stream>>>(verts, colors, faces, out,
                                                    V, F, C);
  }
}